// Round 7
// baseline (13986.391 us; speedup 1.0000x reference)
//
#include <hip/hip_runtime.h>

#define B_  16
#define T_  1024
#define D_  512
#define H_  8
#define L_  6
#define V_  96
#define HS_ 64
#define FF_ 2048
#define BT_ (B_*T_)

// ---------------- zero the loss accumulator ----------------
__global__ void zero_kernel(float* p) { p[0] = 0.f; }

// ---------------- embedding: x[b,t,:] = tok[idx[b,t],:] + pos[t,:] ----------------
__global__ __launch_bounds__(128) void embed_kernel(const int* __restrict__ idx,
    const float* __restrict__ tok, const float* __restrict__ pos, float* __restrict__ x) {
  int bt = blockIdx.x;
  int t  = bt & (T_ - 1);
  int id = idx[bt];
  if (id < 0) id = 0; if (id > V_ - 1) id = V_ - 1;
  int d  = threadIdx.x * 4;
  float4 tv = *(const float4*)(tok + (size_t)id * D_ + d);
  float4 pv = *(const float4*)(pos + (size_t)t  * D_ + d);
  float4 o = {tv.x + pv.x, tv.y + pv.y, tv.z + pv.z, tv.w + pv.w};
  *(float4*)(x + (size_t)bt * D_ + d) = o;
}

// ---------------- layernorm: one wave (64 lanes) per row of D=512 ----------------
__global__ __launch_bounds__(256) void ln_kernel(const float* __restrict__ x,
    const float* __restrict__ s, const float* __restrict__ b, float* __restrict__ out) {
  int wave = threadIdx.x >> 6;
  int lane = threadIdx.x & 63;
  int r = blockIdx.x * 4 + wave;
  const float* xr = x + (size_t)r * D_;
  float vals[8];
  float sum = 0.f;
#pragma unroll
  for (int j = 0; j < 8; ++j) { vals[j] = xr[j * 64 + lane]; sum += vals[j]; }
#pragma unroll
  for (int o = 32; o > 0; o >>= 1) sum += __shfl_xor(sum, o, 64);
  float mean = sum * (1.f / D_);
  float vs = 0.f;
#pragma unroll
  for (int j = 0; j < 8; ++j) { float d = vals[j] - mean; vs += d * d; }
#pragma unroll
  for (int o = 32; o > 0; o >>= 1) vs += __shfl_xor(vs, o, 64);
  float rstd = rsqrtf(vs * (1.f / D_) + 1e-5f);
  float* orow = out + (size_t)r * D_;
#pragma unroll
  for (int j = 0; j < 8; ++j) {
    int c = j * 64 + lane;
    orow[c] = (vals[j] - mean) * rstd * s[c] + b[c];
  }
}

// ---------------- generic f32 tiled GEMM: C[M,N] (+)= A[M,K] @ Bw[K,N] ----------------
// 64x64 tile, 256 thr, 4x4/thr. Bw row-major with leading dim ldb.
template<bool ACC, bool RELU, bool BIAS>
__device__ __forceinline__ void gemm_tile_dev(const float* __restrict__ A, int lda,
    const float* __restrict__ Bw, int ldb, const float* __restrict__ bias,
    float* __restrict__ C, int ldc, int K, int m0, int n0, int nvalid) {
  __shared__ float As[16][64];
  __shared__ float Bs[16][64];
  const int tid = threadIdx.x;
  const int tx = tid & 15, ty = tid >> 4;
  const int amm = tid >> 2;
  const int akk = (tid & 3) * 4;
  const int bkk = tid >> 4;
  const int bnn = (tid & 15) * 4;
  float acc[4][4] = {};
  for (int k0 = 0; k0 < K; k0 += 16) {
    float4 av = *(const float4*)(A + (size_t)(m0 + amm) * lda + k0 + akk);
    As[akk + 0][amm] = av.x; As[akk + 1][amm] = av.y;
    As[akk + 2][amm] = av.z; As[akk + 3][amm] = av.w;
    if (bnn < nvalid) {
      float4 bv = *(const float4*)(Bw + (size_t)(k0 + bkk) * ldb + n0 + bnn);
      Bs[bkk][bnn + 0] = bv.x; Bs[bkk][bnn + 1] = bv.y;
      Bs[bkk][bnn + 2] = bv.z; Bs[bkk][bnn + 3] = bv.w;
    } else {
      Bs[bkk][bnn + 0] = 0.f; Bs[bkk][bnn + 1] = 0.f;
      Bs[bkk][bnn + 2] = 0.f; Bs[bkk][bnn + 3] = 0.f;
    }
    __syncthreads();
#pragma unroll
    for (int kk = 0; kk < 16; ++kk) {
      float4 a4 = *(const float4*)(&As[kk][ty * 4]);
      float4 b4 = *(const float4*)(&Bs[kk][tx * 4]);
      float aa[4] = {a4.x, a4.y, a4.z, a4.w};
      float bb[4] = {b4.x, b4.y, b4.z, b4.w};
#pragma unroll
      for (int i = 0; i < 4; ++i)
#pragma unroll
        for (int j = 0; j < 4; ++j)
          acc[i][j] = fmaf(aa[i], bb[j], acc[i][j]);
    }
    __syncthreads();
  }
  if (tx * 4 < nvalid) {
#pragma unroll
    for (int i = 0; i < 4; ++i) {
      float* cp = C + (size_t)(m0 + ty * 4 + i) * ldc + n0 + tx * 4;
      float r0 = acc[i][0], r1 = acc[i][1], r2 = acc[i][2], r3 = acc[i][3];
      if (BIAS) {
        r0 += bias[n0 + tx * 4 + 0]; r1 += bias[n0 + tx * 4 + 1];
        r2 += bias[n0 + tx * 4 + 2]; r3 += bias[n0 + tx * 4 + 3];
      }
      if (RELU) { r0 = fmaxf(r0, 0.f); r1 = fmaxf(r1, 0.f); r2 = fmaxf(r2, 0.f); r3 = fmaxf(r3, 0.f); }
      if (ACC) {
        float4 c4 = *(const float4*)cp;
        r0 += c4.x; r1 += c4.y; r2 += c4.z; r3 += c4.w;
      }
      float4 st = {r0, r1, r2, r3};
      *(float4*)cp = st;
    }
  }
}

template<bool ACC, bool RELU>
__global__ __launch_bounds__(256) void gemm_kernel(const float* __restrict__ A, int lda,
    const float* __restrict__ Bw, int ldb, const float* __restrict__ bias,
    float* __restrict__ C, int ldc, int K, int N) {
  int n0 = blockIdx.y * 64;
  int nv = N - n0; if (nv > 64) nv = 64;
  gemm_tile_dev<ACC, RELU, true>(A, lda, Bw, ldb, bias, C, ldc, K, blockIdx.x * 64, n0, nv);
}

// per-head projection: out[(b*H+h)*T*HS + t*HS + k] = h_act[b] @ W[h]  (M=T,N=HS,K=D)
__global__ __launch_bounds__(256) void gemm_head_kernel(const float* __restrict__ A,
    const float* __restrict__ Bw, float* __restrict__ C) {
  int z = blockIdx.z;
  int b = z >> 3, hh = z & 7;
  gemm_tile_dev<false, false, false>(A + (size_t)b * T_ * D_, D_,
      Bw + (size_t)hh * D_ * HS_, HS_, nullptr,
      C + (size_t)z * T_ * HS_, HS_, D_, blockIdx.x * 64, 0, 64);
}

// ---------------- flash-style causal attention, f32. One block = 64 q-rows of one (b,h) ----
__global__ __launch_bounds__(256) void attn_kernel(const float* __restrict__ q,
    const float* __restrict__ k, const float* __restrict__ v, float* __restrict__ o) {
  __shared__ float Qs[64][65];
  __shared__ float Ks[64][65];   // reused as P (post-softmax scores)
  __shared__ float Vs[64][65];
  __shared__ float rowm[64], rowl[64], ralpha[64];
  const int qt = blockIdx.x;
  const int bh = blockIdx.y;
  const int b = bh >> 3, hh = bh & 7;
  const float* qb = q + (size_t)bh * T_ * HS_;
  const float* kb = k + (size_t)bh * T_ * HS_;
  const float* vb = v + (size_t)bh * T_ * HS_;
  const int tid = threadIdx.x;
  const int tx = tid & 15, ty = tid >> 4;
  const float scale = 0.044194173824159216f;  // 512^-0.5 (reference scales by D, not HS)

#pragma unroll
  for (int rep = 0; rep < 4; ++rep) {
    int li = rep * 256 + tid;
    int row = li >> 4, c4 = (li & 15) * 4;
    float4 qv = *(const float4*)(qb + (size_t)(qt * 64 + row) * HS_ + c4);
    Qs[row][c4 + 0] = qv.x * scale; Qs[row][c4 + 1] = qv.y * scale;
    Qs[row][c4 + 2] = qv.z * scale; Qs[row][c4 + 3] = qv.w * scale;
  }
  if (tid < 64) { rowm[tid] = -INFINITY; rowl[tid] = 0.f; }
  float acc[4][4] = {};
  const int nkt = qt + 1;
  for (int kt = 0; kt < nkt; ++kt) {
    __syncthreads();
#pragma unroll
    for (int rep = 0; rep < 4; ++rep) {
      int li = rep * 256 + tid;
      int row = li >> 4, c4 = (li & 15) * 4;
      float4 kv = *(const float4*)(kb + (size_t)(kt * 64 + row) * HS_ + c4);
      Ks[row][c4 + 0] = kv.x; Ks[row][c4 + 1] = kv.y; Ks[row][c4 + 2] = kv.z; Ks[row][c4 + 3] = kv.w;
      float4 vv = *(const float4*)(vb + (size_t)(kt * 64 + row) * HS_ + c4);
      Vs[row][c4 + 0] = vv.x; Vs[row][c4 + 1] = vv.y; Vs[row][c4 + 2] = vv.z; Vs[row][c4 + 3] = vv.w;
    }
    __syncthreads();
    float s4[4][4] = {};
    for (int c = 0; c < 64; ++c) {
      float aa[4], bb[4];
#pragma unroll
      for (int i = 0; i < 4; ++i) aa[i] = Qs[ty * 4 + i][c];
#pragma unroll
      for (int j = 0; j < 4; ++j) bb[j] = Ks[tx * 4 + j][c];
#pragma unroll
      for (int i = 0; i < 4; ++i)
#pragma unroll
        for (int j = 0; j < 4; ++j)
          s4[i][j] = fmaf(aa[i], bb[j], s4[i][j]);
    }
    __syncthreads();
    const bool diag = (kt == qt);
#pragma unroll
    for (int i = 0; i < 4; ++i)
#pragma unroll
      for (int j = 0; j < 4; ++j) {
        float sv = s4[i][j];
        if (diag) {
          int gr = qt * 64 + ty * 4 + i, gc = kt * 64 + tx * 4 + j;
          if (gc > gr) sv = -INFINITY;
        }
        Ks[ty * 4 + i][tx * 4 + j] = sv;
      }
    __syncthreads();
    if (tid < 64) {
      int r = tid;
      float mloc = -INFINITY;
      for (int j2 = 0; j2 < 64; ++j2) mloc = fmaxf(mloc, Ks[r][j2]);
      float mold = rowm[r];
      float mnew = fmaxf(mold, mloc);
      float alpha = (mold == -INFINITY) ? 0.f : expf(mold - mnew);
      float ssum = 0.f;
      for (int j2 = 0; j2 < 64; ++j2) {
        float p = expf(Ks[r][j2] - mnew);
        Ks[r][j2] = p;
        ssum += p;
      }
      rowl[r] = alpha * rowl[r] + ssum;
      rowm[r] = mnew;
      ralpha[r] = alpha;
    }
    __syncthreads();
    float al[4];
#pragma unroll
    for (int i = 0; i < 4; ++i) al[i] = ralpha[ty * 4 + i];
#pragma unroll
    for (int i = 0; i < 4; ++i)
#pragma unroll
      for (int j = 0; j < 4; ++j) acc[i][j] *= al[i];
    for (int s2 = 0; s2 < 64; ++s2) {
      float pp[4], ww[4];
#pragma unroll
      for (int i = 0; i < 4; ++i) pp[i] = Ks[ty * 4 + i][s2];
#pragma unroll
      for (int j = 0; j < 4; ++j) ww[j] = Vs[s2][tx * 4 + j];
#pragma unroll
      for (int i = 0; i < 4; ++i)
#pragma unroll
        for (int j = 0; j < 4; ++j)
          acc[i][j] = fmaf(pp[i], ww[j], acc[i][j]);
    }
  }
  // concat-head layout o[b, t, hh*HS + c]
#pragma unroll
  for (int i = 0; i < 4; ++i) {
    float inv = 1.f / rowl[ty * 4 + i];
    int gr = qt * 64 + ty * 4 + i;
    float4 st = {acc[i][0] * inv, acc[i][1] * inv, acc[i][2] * inv, acc[i][3] * inv};
    *(float4*)(o + ((size_t)(b * T_ + gr)) * D_ + hh * HS_ + tx * 4) = st;
  }
}

// ---------------- loss: logits already in out (f32); accumulate mean NLL ----------------
__global__ __launch_bounds__(256) void loss_kernel(const float* __restrict__ logits,
    const int* __restrict__ targets, float* __restrict__ loss_acc) {
  int wave = threadIdx.x >> 6, lane = threadIdx.x & 63;
  int r = blockIdx.x * 4 + wave;
  const float* lr = logits + (size_t)r * V_;
  float v0 = lr[lane];
  float v1 = (lane < 32) ? lr[64 + lane] : -INFINITY;
  float mx = fmaxf(v0, v1);
#pragma unroll
  for (int o = 32; o > 0; o >>= 1) mx = fmaxf(mx, __shfl_xor(mx, o, 64));
  float se = expf(v0 - mx) + ((lane < 32) ? expf(v1 - mx) : 0.f);
#pragma unroll
  for (int o = 32; o > 0; o >>= 1) se += __shfl_xor(se, o, 64);
  if (lane == 0) {
    float logZ = mx + logf(se);
    int tg = targets[r];
    if (tg < 0) tg = 0; if (tg > V_ - 1) tg = V_ - 1;
    atomicAdd(loss_acc, logZ - lr[tg]);
  }
}

__global__ void loss_finalize_kernel(const float* __restrict__ acc, float* __restrict__ out) {
  out[(size_t)BT_ * V_] = acc[0] * (1.f / BT_);
}

// ---------------- host ----------------
// Workspace (f32): x,h,qb,kb,vb (5 x BT*D) + ff (BT*FF) + lacc pad = ~302 MB.
// If harness d_ws is smaller, hipMalloc once on the first (non-captured) call.
static void* g_ws_fallback = nullptr;

extern "C" void kernel_launch(void* const* d_in, const int* in_sizes, int n_in,
                              void* d_out, int out_size, void* d_ws, size_t ws_size,
                              hipStream_t stream) {
  const int*   idx     = (const int*)d_in[0];
  const int*   targets = (const int*)d_in[1];
  const float* tok  = (const float*)d_in[2];
  const float* pos  = (const float*)d_in[3];
  const float* Wq   = (const float*)d_in[4];
  const float* Wk   = (const float*)d_in[5];
  const float* Wv   = (const float*)d_in[6];
  const float* Wp   = (const float*)d_in[7];
  const float* bp   = (const float*)d_in[8];
  const float* W1   = (const float*)d_in[9];
  const float* b1   = (const float*)d_in[10];
  const float* W2   = (const float*)d_in[11];
  const float* b2   = (const float*)d_in[12];
  const float* l1s  = (const float*)d_in[13];
  const float* l1b  = (const float*)d_in[14];
  const float* l2s  = (const float*)d_in[15];
  const float* l2b  = (const float*)d_in[16];
  const float* lfs  = (const float*)d_in[17];
  const float* lfb  = (const float*)d_in[18];
  const float* Wout = (const float*)d_in[19];
  const float* bout = (const float*)d_in[20];
  float* out = (float*)d_out;   // f32 logits (BT*V) then f32 loss scalar

  const size_t n_x  = (size_t)BT_ * D_;
  const size_t n_ff = (size_t)BT_ * FF_;
  const size_t need_floats = 5 * n_x + n_ff + 256;
  const size_t need_bytes  = need_floats * sizeof(float);

  float* ws;
  if (ws_size >= need_bytes) {
    ws = (float*)d_ws;
  } else {
    if (!g_ws_fallback) (void)hipMalloc(&g_ws_fallback, need_bytes);
    ws = (float*)g_ws_fallback;
  }

  size_t off = 0;
  float* x   = ws + off; off += n_x;
  float* h   = ws + off; off += n_x;   // ln out, reused as attention out
  float* qb  = ws + off; off += n_x;
  float* kb  = ws + off; off += n_x;
  float* vb  = ws + off; off += n_x;
  float* ff  = ws + off; off += n_ff;
  float* lacc = ws + off;

  zero_kernel<<<1, 1, 0, stream>>>(lacc);
  embed_kernel<<<BT_, 128, 0, stream>>>(idx, tok, pos, x);

  for (int l = 0; l < L_; ++l) {
    ln_kernel<<<BT_ / 4, 256, 0, stream>>>(x, l1s + (size_t)l * D_, l1b + (size_t)l * D_, h);
    dim3 gq(T_ / 64, 1, B_ * H_);
    gemm_head_kernel<<<gq, 256, 0, stream>>>(h, Wq + (size_t)l * H_ * D_ * HS_, qb);
    gemm_head_kernel<<<gq, 256, 0, stream>>>(h, Wk + (size_t)l * H_ * D_ * HS_, kb);
    gemm_head_kernel<<<gq, 256, 0, stream>>>(h, Wv + (size_t)l * H_ * D_ * HS_, vb);
    attn_kernel<<<dim3(T_ / 64, B_ * H_), 256, 0, stream>>>(qb, kb, vb, h);
    gemm_kernel<true, false><<<dim3(BT_ / 64, D_ / 64), 256, 0, stream>>>(
        h, D_, Wp + (size_t)l * D_ * D_, D_, bp + (size_t)l * D_, x, D_, D_, D_);
    ln_kernel<<<BT_ / 4, 256, 0, stream>>>(x, l2s + (size_t)l * D_, l2b + (size_t)l * D_, h);
    gemm_kernel<false, true><<<dim3(BT_ / 64, FF_ / 64), 256, 0, stream>>>(
        h, D_, W1 + (size_t)l * D_ * FF_, FF_, b1 + (size_t)l * FF_, ff, FF_, D_, FF_);
    gemm_kernel<true, false><<<dim3(BT_ / 64, D_ / 64), 256, 0, stream>>>(
        ff, FF_, W2 + (size_t)l * FF_ * D_, D_, b2 + (size_t)l * D_, x, D_, FF_, D_);
  }

  ln_kernel<<<BT_ / 4, 256, 0, stream>>>(x, lfs, lfb, h);
  // logits straight into d_out (f32), N=96 -> grid.y=2 with nvalid clamp
  gemm_kernel<false, false><<<dim3(BT_ / 64, 2), 256, 0, stream>>>(
      h, D_, Wout, V_, bout, out, V_, D_, V_);
  loss_kernel<<<BT_ / 4, 256, 0, stream>>>(out, targets, lacc);
  loss_finalize_kernel<<<1, 1, 0, stream>>>(lacc, out);
}

// Round 8
// 6914.349 us; speedup vs baseline: 2.0228x; 2.0228x over previous
//
#include <hip/hip_runtime.h>

#define B_  16
#define T_  1024
#define D_  512
#define H_  8
#define L_  6
#define V_  96
#define HS_ 64
#define FF_ 2048
#define BT_ (B_*T_)

typedef __attribute__((ext_vector_type(8))) short bf16x8;
typedef __attribute__((ext_vector_type(4))) float f32x4;

__device__ __forceinline__ unsigned short f2b(float f) {
  unsigned u = __float_as_uint(f);
  unsigned r = (u + 0x7FFFu + ((u >> 16) & 1u)) >> 16;
  return (unsigned short)r;
}

// ---------------- zero the loss accumulator ----------------
__global__ void zero_kernel(float* p) { p[0] = 0.f; }

// ---------------- embedding: x[b,t,:] = tok[idx[b,t],:] + pos[t,:] ----------------
__global__ __launch_bounds__(128) void embed_kernel(const int* __restrict__ idx,
    const float* __restrict__ tok, const float* __restrict__ pos, float* __restrict__ x) {
  int bt = blockIdx.x;
  int t  = bt & (T_ - 1);
  int id = idx[bt];
  if (id < 0) id = 0; if (id > V_ - 1) id = V_ - 1;
  int d  = threadIdx.x * 4;
  float4 tv = *(const float4*)(tok + (size_t)id * D_ + d);
  float4 pv = *(const float4*)(pos + (size_t)t  * D_ + d);
  float4 o = {tv.x + pv.x, tv.y + pv.y, tv.z + pv.z, tv.w + pv.w};
  *(float4*)(x + (size_t)bt * D_ + d) = o;
}

// ---------------- tiled transpose + f32->bf16: dst[C][R] = src[R][C] ----------------
__global__ __launch_bounds__(256) void transpose_cvt(const float* __restrict__ src,
    unsigned short* __restrict__ dst, int R, int C, long sstride, long dstride) {
  __shared__ float t[32][33];
  const float* s = src + (size_t)blockIdx.z * sstride;
  unsigned short* d = dst + (size_t)blockIdx.z * dstride;
  int r0 = blockIdx.y * 32, c0 = blockIdx.x * 32;
  int tr = threadIdx.x >> 5, tc = threadIdx.x & 31;
#pragma unroll
  for (int i = 0; i < 4; ++i)
    t[tr + i * 8][tc] = s[(size_t)(r0 + tr + i * 8) * C + c0 + tc];
  __syncthreads();
#pragma unroll
  for (int i = 0; i < 4; ++i)
    d[(size_t)(c0 + tr + i * 8) * R + r0 + tc] = f2b(t[tc][tr + i * 8]);
}

// ---------------- layernorm: one wave per row; bf16 or f32 out ----------------
template<bool BF16OUT>
__global__ __launch_bounds__(256) void ln_kernel(const float* __restrict__ x,
    const float* __restrict__ s, const float* __restrict__ b, void* __restrict__ outv) {
  int wave = threadIdx.x >> 6;
  int lane = threadIdx.x & 63;
  int r = blockIdx.x * 4 + wave;
  const float* xr = x + (size_t)r * D_;
  float vals[8];
  float sum = 0.f;
#pragma unroll
  for (int j = 0; j < 8; ++j) { vals[j] = xr[j * 64 + lane]; sum += vals[j]; }
#pragma unroll
  for (int o = 32; o > 0; o >>= 1) sum += __shfl_xor(sum, o, 64);
  float mean = sum * (1.f / D_);
  float vs = 0.f;
#pragma unroll
  for (int j = 0; j < 8; ++j) { float d = vals[j] - mean; vs += d * d; }
#pragma unroll
  for (int o = 32; o > 0; o >>= 1) vs += __shfl_xor(vs, o, 64);
  float rstd = rsqrtf(vs * (1.f / D_) + 1e-5f);
#pragma unroll
  for (int j = 0; j < 8; ++j) {
    int c = j * 64 + lane;
    float v = (vals[j] - mean) * rstd * s[c] + b[c];
    if (BF16OUT) ((unsigned short*)outv)[(size_t)r * D_ + c] = f2b(v);
    else         ((float*)outv)[(size_t)r * D_ + c] = v;
  }
}

// ---------------- bf16 MFMA GEMM: C[M,N] (+)= A[M,K] @ Bt[N,K]^T ----------------
// 128x128 tile, BK=32, 256 thr / 4 waves, each wave 64x64 via 4x4 16x16x32 MFMA.
#define LROW 40   // LDS row stride in bf16 elems (32 + 8 pad)
template<bool ACC, bool RELU, bool BIAS, bool OUTBF16>
__global__ __launch_bounds__(256) void mfma_gemm(
    const unsigned short* __restrict__ A,   // [M][K] bf16
    const unsigned short* __restrict__ Bt,  // [N][K] bf16
    const float* __restrict__ bias,         // [N] f32 (if BIAS)
    void* __restrict__ Cv,                  // f32 or bf16 [M][ldc]
    int K, int ldc) {
  __shared__ unsigned short Al[128 * LROW];
  __shared__ unsigned short Bl[128 * LROW];
  const int m0 = blockIdx.x * 128, n0 = blockIdx.y * 128;
  const int tid = threadIdx.x;
  const int lane = tid & 63, wave = tid >> 6;
  const int wy = wave >> 1, wx = wave & 1;
  const int l15 = lane & 15, quad = lane >> 4;
  f32x4 acc[4][4];
  const f32x4 z4 = {0.f, 0.f, 0.f, 0.f};
#pragma unroll
  for (int mi = 0; mi < 4; ++mi)
#pragma unroll
    for (int ni = 0; ni < 4; ++ni) acc[mi][ni] = z4;

  for (int k0 = 0; k0 < K; k0 += 32) {
#pragma unroll
    for (int i = 0; i < 2; ++i) {
      int c = tid + 256 * i;
      int row = c >> 2, kc = (c & 3) * 8;
      bf16x8 av = *(const bf16x8*)(A + (size_t)(m0 + row) * K + k0 + kc);
      *(bf16x8*)(&Al[row * LROW + kc]) = av;
      bf16x8 bv = *(const bf16x8*)(Bt + (size_t)(n0 + row) * K + k0 + kc);
      *(bf16x8*)(&Bl[row * LROW + kc]) = bv;
    }
    __syncthreads();
    bf16x8 af[4], bfr[4];
#pragma unroll
    for (int mi = 0; mi < 4; ++mi)
      af[mi] = *(const bf16x8*)(&Al[(wy * 64 + mi * 16 + l15) * LROW + quad * 8]);
#pragma unroll
    for (int ni = 0; ni < 4; ++ni)
      bfr[ni] = *(const bf16x8*)(&Bl[(wx * 64 + ni * 16 + l15) * LROW + quad * 8]);
#pragma unroll
    for (int mi = 0; mi < 4; ++mi)
#pragma unroll
      for (int ni = 0; ni < 4; ++ni)
        acc[mi][ni] = __builtin_amdgcn_mfma_f32_16x16x32_bf16(af[mi], bfr[ni], acc[mi][ni], 0, 0, 0);
    __syncthreads();
  }
  // epilogue: C/D layout col=lane&15, row=quad*4+reg
#pragma unroll
  for (int mi = 0; mi < 4; ++mi) {
    int row0 = m0 + wy * 64 + mi * 16 + quad * 4;
#pragma unroll
    for (int ni = 0; ni < 4; ++ni) {
      int col = n0 + wx * 64 + ni * 16 + l15;
      float bb = BIAS ? bias[col] : 0.f;
#pragma unroll
      for (int r = 0; r < 4; ++r) {
        float v = acc[mi][ni][r] + bb;
        if (RELU) v = fmaxf(v, 0.f);
        size_t off = (size_t)(row0 + r) * ldc + col;
        if (ACC) v += ((const float*)Cv)[off];
        if (OUTBF16) ((unsigned short*)Cv)[off] = f2b(v);
        else         ((float*)Cv)[off] = v;
      }
    }
  }
}

// ---------------- f32 tiled GEMM (logits only): C[M,N] = A[M,K]@Bw[K,N] + bias ----------
__global__ __launch_bounds__(256) void gemm_f32_kernel(const float* __restrict__ A, int lda,
    const float* __restrict__ Bw, int ldb, const float* __restrict__ bias,
    float* __restrict__ C, int ldc, int K, int N) {
  __shared__ float As[16][64];
  __shared__ float Bs[16][64];
  int n0 = blockIdx.y * 64;
  int nv = N - n0; if (nv > 64) nv = 64;
  int m0 = blockIdx.x * 64;
  const int tid = threadIdx.x;
  const int tx = tid & 15, ty = tid >> 4;
  const int amm = tid >> 2;
  const int akk = (tid & 3) * 4;
  const int bkk = tid >> 4;
  const int bnn = (tid & 15) * 4;
  float acc[4][4] = {};
  for (int k0 = 0; k0 < K; k0 += 16) {
    float4 av = *(const float4*)(A + (size_t)(m0 + amm) * lda + k0 + akk);
    As[akk + 0][amm] = av.x; As[akk + 1][amm] = av.y;
    As[akk + 2][amm] = av.z; As[akk + 3][amm] = av.w;
    if (bnn < nv) {
      float4 bv = *(const float4*)(Bw + (size_t)(k0 + bkk) * ldb + n0 + bnn);
      Bs[bkk][bnn + 0] = bv.x; Bs[bkk][bnn + 1] = bv.y;
      Bs[bkk][bnn + 2] = bv.z; Bs[bkk][bnn + 3] = bv.w;
    } else {
      Bs[bkk][bnn + 0] = 0.f; Bs[bkk][bnn + 1] = 0.f;
      Bs[bkk][bnn + 2] = 0.f; Bs[bkk][bnn + 3] = 0.f;
    }
    __syncthreads();
#pragma unroll
    for (int kk = 0; kk < 16; ++kk) {
      float4 a4 = *(const float4*)(&As[kk][ty * 4]);
      float4 b4 = *(const float4*)(&Bs[kk][tx * 4]);
      float aa[4] = {a4.x, a4.y, a4.z, a4.w};
      float bb[4] = {b4.x, b4.y, b4.z, b4.w};
#pragma unroll
      for (int i = 0; i < 4; ++i)
#pragma unroll
        for (int j = 0; j < 4; ++j)
          acc[i][j] = fmaf(aa[i], bb[j], acc[i][j]);
    }
    __syncthreads();
  }
  if (tx * 4 < nv) {
#pragma unroll
    for (int i = 0; i < 4; ++i) {
      float* cp = C + (size_t)(m0 + ty * 4 + i) * ldc + n0 + tx * 4;
      float4 st = {acc[i][0] + bias[n0 + tx * 4 + 0], acc[i][1] + bias[n0 + tx * 4 + 1],
                   acc[i][2] + bias[n0 + tx * 4 + 2], acc[i][3] + bias[n0 + tx * 4 + 3]};
      *(float4*)cp = st;
    }
  }
}

// ---------------- flash attention f32; QKV in fused [BT][D] layout; bf16 out ----------
__global__ __launch_bounds__(256) void attn_kernel(const float* __restrict__ q,
    const float* __restrict__ k, const float* __restrict__ v, unsigned short* __restrict__ o) {
  __shared__ float Qs[64][65];
  __shared__ float Ks[64][65];   // reused as P after S
  __shared__ float Vs[64][65];
  __shared__ float rowm[64], rowl[64], ralpha[64];
  const int qt = blockIdx.x;
  const int bh = blockIdx.y;
  const int b = bh >> 3, hh = bh & 7;
  const float* qh = q + (size_t)b * T_ * D_ + hh * HS_;
  const float* kh = k + (size_t)b * T_ * D_ + hh * HS_;
  const float* vh = v + (size_t)b * T_ * D_ + hh * HS_;
  const int tid = threadIdx.x;
  const int tx = tid & 15, ty = tid >> 4;
  const float scale = 0.044194173824159216f;  // 512^-0.5 (reference scales by D)

#pragma unroll
  for (int rep = 0; rep < 4; ++rep) {
    int li = rep * 256 + tid;
    int row = li >> 4, c4 = (li & 15) * 4;
    float4 qv = *(const float4*)(qh + (size_t)(qt * 64 + row) * D_ + c4);
    Qs[row][c4 + 0] = qv.x * scale; Qs[row][c4 + 1] = qv.y * scale;
    Qs[row][c4 + 2] = qv.z * scale; Qs[row][c4 + 3] = qv.w * scale;
  }
  if (tid < 64) { rowm[tid] = -INFINITY; rowl[tid] = 0.f; }
  float acc[4][4] = {};
  const int nkt = qt + 1;
  for (int kt = 0; kt < nkt; ++kt) {
    __syncthreads();
#pragma unroll
    for (int rep = 0; rep < 4; ++rep) {
      int li = rep * 256 + tid;
      int row = li >> 4, c4 = (li & 15) * 4;
      float4 kv = *(const float4*)(kh + (size_t)(kt * 64 + row) * D_ + c4);
      Ks[row][c4 + 0] = kv.x; Ks[row][c4 + 1] = kv.y; Ks[row][c4 + 2] = kv.z; Ks[row][c4 + 3] = kv.w;
      float4 vv = *(const float4*)(vh + (size_t)(kt * 64 + row) * D_ + c4);
      Vs[row][c4 + 0] = vv.x; Vs[row][c4 + 1] = vv.y; Vs[row][c4 + 2] = vv.z; Vs[row][c4 + 3] = vv.w;
    }
    __syncthreads();
    float s4[4][4] = {};
    for (int c = 0; c < 64; ++c) {
      float aa[4], bb[4];
#pragma unroll
      for (int i = 0; i < 4; ++i) aa[i] = Qs[ty * 4 + i][c];
#pragma unroll
      for (int j = 0; j < 4; ++j) bb[j] = Ks[tx * 4 + j][c];
#pragma unroll
      for (int i = 0; i < 4; ++i)
#pragma unroll
        for (int j = 0; j < 4; ++j)
          s4[i][j] = fmaf(aa[i], bb[j], s4[i][j]);
    }
    __syncthreads();
    const bool diag = (kt == qt);
#pragma unroll
    for (int i = 0; i < 4; ++i)
#pragma unroll
      for (int j = 0; j < 4; ++j) {
        float sv = s4[i][j];
        if (diag) {
          int gr = qt * 64 + ty * 4 + i, gc = kt * 64 + tx * 4 + j;
          if (gc > gr) sv = -INFINITY;
        }
        Ks[ty * 4 + i][tx * 4 + j] = sv;
      }
    __syncthreads();
    if (tid < 64) {
      int r = tid;
      float mloc = -INFINITY;
      for (int j2 = 0; j2 < 64; ++j2) mloc = fmaxf(mloc, Ks[r][j2]);
      float mold = rowm[r];
      float mnew = fmaxf(mold, mloc);
      float alpha = (mold == -INFINITY) ? 0.f : expf(mold - mnew);
      float ssum = 0.f;
      for (int j2 = 0; j2 < 64; ++j2) {
        float p = expf(Ks[r][j2] - mnew);
        Ks[r][j2] = p;
        ssum += p;
      }
      rowl[r] = alpha * rowl[r] + ssum;
      rowm[r] = mnew;
      ralpha[r] = alpha;
    }
    __syncthreads();
    float al[4];
#pragma unroll
    for (int i = 0; i < 4; ++i) al[i] = ralpha[ty * 4 + i];
#pragma unroll
    for (int i = 0; i < 4; ++i)
#pragma unroll
      for (int j = 0; j < 4; ++j) acc[i][j] *= al[i];
    for (int s2 = 0; s2 < 64; ++s2) {
      float pp[4], ww[4];
#pragma unroll
      for (int i = 0; i < 4; ++i) pp[i] = Ks[ty * 4 + i][s2];
#pragma unroll
      for (int j = 0; j < 4; ++j) ww[j] = Vs[s2][tx * 4 + j];
#pragma unroll
      for (int i = 0; i < 4; ++i)
#pragma unroll
        for (int j = 0; j < 4; ++j)
          acc[i][j] = fmaf(pp[i], ww[j], acc[i][j]);
    }
  }
  // bf16 out, concat-head layout o[b, t, hh*HS + c]
#pragma unroll
  for (int i = 0; i < 4; ++i) {
    float inv = 1.f / rowl[ty * 4 + i];
    int gr = qt * 64 + ty * 4 + i;
    ushort4 st = {f2b(acc[i][0] * inv), f2b(acc[i][1] * inv),
                  f2b(acc[i][2] * inv), f2b(acc[i][3] * inv)};
    *(ushort4*)(o + ((size_t)(b * T_ + gr)) * D_ + hh * HS_ + tx * 4) = st;
  }
}

// ---------------- loss ----------------
__global__ __launch_bounds__(256) void loss_kernel(const float* __restrict__ logits,
    const int* __restrict__ targets, float* __restrict__ loss_acc) {
  int wave = threadIdx.x >> 6, lane = threadIdx.x & 63;
  int r = blockIdx.x * 4 + wave;
  const float* lr = logits + (size_t)r * V_;
  float v0 = lr[lane];
  float v1 = (lane < 32) ? lr[64 + lane] : -INFINITY;
  float mx = fmaxf(v0, v1);
#pragma unroll
  for (int o = 32; o > 0; o >>= 1) mx = fmaxf(mx, __shfl_xor(mx, o, 64));
  float se = expf(v0 - mx) + ((lane < 32) ? expf(v1 - mx) : 0.f);
#pragma unroll
  for (int o = 32; o > 0; o >>= 1) se += __shfl_xor(se, o, 64);
  if (lane == 0) {
    float logZ = mx + logf(se);
    int tg = targets[r];
    if (tg < 0) tg = 0; if (tg > V_ - 1) tg = V_ - 1;
    atomicAdd(loss_acc, logZ - lr[tg]);
  }
}

__global__ void loss_finalize_kernel(const float* __restrict__ acc, float* __restrict__ out) {
  out[(size_t)BT_ * V_] = acc[0] * (1.f / BT_);
}

// ---------------- host ----------------
static void* g_ws_fallback = nullptr;

extern "C" void kernel_launch(void* const* d_in, const int* in_sizes, int n_in,
                              void* d_out, int out_size, void* d_ws, size_t ws_size,
                              hipStream_t stream) {
  const int*   idx     = (const int*)d_in[0];
  const int*   targets = (const int*)d_in[1];
  const float* tok  = (const float*)d_in[2];
  const float* pos  = (const float*)d_in[3];
  const float* Wq   = (const float*)d_in[4];
  const float* Wk   = (const float*)d_in[5];
  const float* Wv   = (const float*)d_in[6];
  const float* Wp   = (const float*)d_in[7];
  const float* bp   = (const float*)d_in[8];
  const float* W1   = (const float*)d_in[9];
  const float* b1   = (const float*)d_in[10];
  const float* W2   = (const float*)d_in[11];
  const float* b2   = (const float*)d_in[12];
  const float* l1s  = (const float*)d_in[13];
  const float* l1b  = (const float*)d_in[14];
  const float* l2s  = (const float*)d_in[15];
  const float* l2b  = (const float*)d_in[16];
  const float* lfs  = (const float*)d_in[17];
  const float* lfb  = (const float*)d_in[18];
  const float* Wout = (const float*)d_in[19];
  const float* bout = (const float*)d_in[20];
  float* out = (float*)d_out;   // f32 logits (BT*V) + f32 loss scalar

  const size_t n_x   = (size_t)BT_ * D_;   // f32 elems
  const size_t n_ffh = (size_t)BT_ * FF_ / 2;  // bf16 as f32-equiv
  const size_t n_hb  = n_x / 2;
  const size_t n_wT  = 9437184;            // all transposed bf16 weights, f32-equiv
  const size_t need_floats = 4 * n_x + n_ffh + n_hb + n_wT + 256;
  const size_t need_bytes  = need_floats * sizeof(float);

  float* ws;
  if (ws_size >= need_bytes) {
    ws = (float*)d_ws;
  } else {
    if (!g_ws_fallback) (void)hipMalloc(&g_ws_fallback, need_bytes);
    ws = (float*)g_ws_fallback;
  }

  size_t off = 0;
  float* x  = ws + off; off += n_x;
  float* qb = ws + off; off += n_x;   // also final-LN f32 buffer
  float* kb = ws + off; off += n_x;
  float* vb = ws + off; off += n_x;
  unsigned short* hb  = (unsigned short*)(ws + off); off += n_hb;
  unsigned short* ffb = (unsigned short*)(ws + off); off += n_ffh;
  unsigned short* wqT = (unsigned short*)(ws + off);  // L*512*512
  unsigned short* wkT = wqT + (size_t)L_ * D_ * D_;
  unsigned short* wvT = wkT + (size_t)L_ * D_ * D_;
  unsigned short* wpT = wvT + (size_t)L_ * D_ * D_;
  unsigned short* w1T = wpT + (size_t)L_ * D_ * D_;
  unsigned short* w2T = w1T + (size_t)L_ * D_ * FF_;
  off += n_wT;
  float* lacc = ws + off;

  zero_kernel<<<1, 1, 0, stream>>>(lacc);
  embed_kernel<<<BT_, 128, 0, stream>>>(idx, tok, pos, x);

  // weights -> bf16 [N][K]
  transpose_cvt<<<dim3(2, 16, 48), 256, 0, stream>>>(Wq, wqT, 512, 64, 32768, 32768);
  transpose_cvt<<<dim3(2, 16, 48), 256, 0, stream>>>(Wk, wkT, 512, 64, 32768, 32768);
  transpose_cvt<<<dim3(2, 16, 48), 256, 0, stream>>>(Wv, wvT, 512, 64, 32768, 32768);
  transpose_cvt<<<dim3(16, 16, 6), 256, 0, stream>>>(Wp, wpT, 512, 512, 262144, 262144);
  transpose_cvt<<<dim3(64, 16, 6), 256, 0, stream>>>(W1, w1T, 512, 2048, 1048576, 1048576);
  transpose_cvt<<<dim3(16, 64, 6), 256, 0, stream>>>(W2, w2T, 2048, 512, 1048576, 1048576);

  const dim3 gD(BT_ / 128, D_ / 128);    // N=512
  const dim3 gF(BT_ / 128, FF_ / 128);   // N=2048

  for (int l = 0; l < L_; ++l) {
    ln_kernel<true><<<BT_ / 4, 256, 0, stream>>>(x, l1s + (size_t)l * D_, l1b + (size_t)l * D_, hb);
    mfma_gemm<false, false, false, false><<<gD, 256, 0, stream>>>(
        hb, wqT + (size_t)l * D_ * D_, nullptr, qb, D_, D_);
    mfma_gemm<false, false, false, false><<<gD, 256, 0, stream>>>(
        hb, wkT + (size_t)l * D_ * D_, nullptr, kb, D_, D_);
    mfma_gemm<false, false, false, false><<<gD, 256, 0, stream>>>(
        hb, wvT + (size_t)l * D_ * D_, nullptr, vb, D_, D_);
    attn_kernel<<<dim3(T_ / 64, B_ * H_), 256, 0, stream>>>(qb, kb, vb, hb);
    mfma_gemm<true, false, true, false><<<gD, 256, 0, stream>>>(
        hb, wpT + (size_t)l * D_ * D_, bp + (size_t)l * D_, x, D_, D_);
    ln_kernel<true><<<BT_ / 4, 256, 0, stream>>>(x, l2s + (size_t)l * D_, l2b + (size_t)l * D_, hb);
    mfma_gemm<false, true, true, true><<<gF, 256, 0, stream>>>(
        hb, w1T + (size_t)l * D_ * FF_, b1 + (size_t)l * FF_, ffb, D_, FF_);
    mfma_gemm<true, false, true, false><<<gD, 256, 0, stream>>>(
        ffb, w2T + (size_t)l * FF_ * D_, b2 + (size_t)l * D_, x, FF_, D_);
  }

  ln_kernel<false><<<BT_ / 4, 256, 0, stream>>>(x, lfs, lfb, qb);
  gemm_f32_kernel<<<dim3(BT_ / 64, 2), 256, 0, stream>>>(
      qb, D_, Wout, V_, bout, out, V_, D_, V_);
  loss_kernel<<<BT_ / 4, 256, 0, stream>>>(out, targets, lacc);
  loss_finalize_kernel<<<1, 1, 0, stream>>>(lacc, out);
}

// Round 9
// 3939.220 us; speedup vs baseline: 3.5505x; 1.7553x over previous
//
#include <hip/hip_runtime.h>

#define B_  16
#define T_  1024
#define D_  512
#define H_  8
#define L_  6
#define V_  96
#define HS_ 64
#define FF_ 2048
#define BT_ (B_*T_)

typedef __attribute__((ext_vector_type(8))) short bf16x8;
typedef __attribute__((ext_vector_type(4))) float f32x4;

__device__ __forceinline__ unsigned short f2b(float f) {
  unsigned u = __float_as_uint(f);
  unsigned r = (u + 0x7FFFu + ((u >> 16) & 1u)) >> 16;
  return (unsigned short)r;
}

__global__ void zero_kernel(float* p) { p[0] = 0.f; }

// ---------------- embedding ----------------
__global__ __launch_bounds__(128) void embed_kernel(const int* __restrict__ idx,
    const float* __restrict__ tok, const float* __restrict__ pos, float* __restrict__ x) {
  int bt = blockIdx.x;
  int t  = bt & (T_ - 1);
  int id = idx[bt];
  if (id < 0) id = 0; if (id > V_ - 1) id = V_ - 1;
  int d  = threadIdx.x * 4;
  float4 tv = *(const float4*)(tok + (size_t)id * D_ + d);
  float4 pv = *(const float4*)(pos + (size_t)t  * D_ + d);
  float4 o = {tv.x + pv.x, tv.y + pv.y, tv.z + pv.z, tv.w + pv.w};
  *(float4*)(x + (size_t)bt * D_ + d) = o;
}

// ---------------- tiled transpose + f32->bf16: dst[C][R] = src[R][C] ----------------
__global__ __launch_bounds__(256) void transpose_cvt(const float* __restrict__ src,
    unsigned short* __restrict__ dst, int R, int C, long sstride, long dstride) {
  __shared__ float t[32][33];
  const float* s = src + (size_t)blockIdx.z * sstride;
  unsigned short* d = dst + (size_t)blockIdx.z * dstride;
  int r0 = blockIdx.y * 32, c0 = blockIdx.x * 32;
  int tr = threadIdx.x >> 5, tc = threadIdx.x & 31;
#pragma unroll
  for (int i = 0; i < 4; ++i)
    t[tr + i * 8][tc] = s[(size_t)(r0 + tr + i * 8) * C + c0 + tc];
  __syncthreads();
#pragma unroll
  for (int i = 0; i < 4; ++i)
    d[(size_t)(c0 + tr + i * 8) * R + r0 + tc] = f2b(t[tc][tr + i * 8]);
}

// ---------------- layernorm: one wave per row; bf16 or f32 out ----------------
template<bool BF16OUT>
__global__ __launch_bounds__(256) void ln_kernel(const float* __restrict__ x,
    const float* __restrict__ s, const float* __restrict__ b, void* __restrict__ outv) {
  int wave = threadIdx.x >> 6;
  int lane = threadIdx.x & 63;
  int r = blockIdx.x * 4 + wave;
  const float* xr = x + (size_t)r * D_;
  float vals[8];
  float sum = 0.f;
#pragma unroll
  for (int j = 0; j < 8; ++j) { vals[j] = xr[j * 64 + lane]; sum += vals[j]; }
#pragma unroll
  for (int o = 32; o > 0; o >>= 1) sum += __shfl_xor(sum, o, 64);
  float mean = sum * (1.f / D_);
  float vs = 0.f;
#pragma unroll
  for (int j = 0; j < 8; ++j) { float d = vals[j] - mean; vs += d * d; }
#pragma unroll
  for (int o = 32; o > 0; o >>= 1) vs += __shfl_xor(vs, o, 64);
  float rstd = rsqrtf(vs * (1.f / D_) + 1e-5f);
#pragma unroll
  for (int j = 0; j < 8; ++j) {
    int c = j * 64 + lane;
    float v = (vals[j] - mean) * rstd * s[c] + b[c];
    if (BF16OUT) ((unsigned short*)outv)[(size_t)r * D_ + c] = f2b(v);
    else         ((float*)outv)[(size_t)r * D_ + c] = v;
  }
}

// ---------------- bf16 MFMA GEMM: C[M,N] (+)= A[M,K] @ Bt[N,K]^T ----------------
// OUTMODE: 0 = f32 [M][ldc], 1 = bf16 [M][ldc], 2 = bf16 Vt[(b*H+h)*HS+hs][T] (V transpose)
#define LROW 40
template<bool ACC, bool RELU, bool BIAS, int OUTMODE>
__global__ __launch_bounds__(256) void mfma_gemm(
    const unsigned short* __restrict__ A,
    const unsigned short* __restrict__ Bt,
    const float* __restrict__ bias,
    void* __restrict__ Cv,
    int K, int ldc) {
  __shared__ unsigned short Al[128 * LROW];
  __shared__ unsigned short Bl[128 * LROW];
  const int m0 = blockIdx.x * 128, n0 = blockIdx.y * 128;
  const int tid = threadIdx.x;
  const int lane = tid & 63, wave = tid >> 6;
  const int wy = wave >> 1, wx = wave & 1;
  const int l15 = lane & 15, quad = lane >> 4;
  f32x4 acc[4][4];
  const f32x4 z4 = {0.f, 0.f, 0.f, 0.f};
#pragma unroll
  for (int mi = 0; mi < 4; ++mi)
#pragma unroll
    for (int ni = 0; ni < 4; ++ni) acc[mi][ni] = z4;

  for (int k0 = 0; k0 < K; k0 += 32) {
#pragma unroll
    for (int i = 0; i < 2; ++i) {
      int c = tid + 256 * i;
      int row = c >> 2, kc = (c & 3) * 8;
      bf16x8 av = *(const bf16x8*)(A + (size_t)(m0 + row) * K + k0 + kc);
      *(bf16x8*)(&Al[row * LROW + kc]) = av;
      bf16x8 bv = *(const bf16x8*)(Bt + (size_t)(n0 + row) * K + k0 + kc);
      *(bf16x8*)(&Bl[row * LROW + kc]) = bv;
    }
    __syncthreads();
    bf16x8 af[4], bfr[4];
#pragma unroll
    for (int mi = 0; mi < 4; ++mi)
      af[mi] = *(const bf16x8*)(&Al[(wy * 64 + mi * 16 + l15) * LROW + quad * 8]);
#pragma unroll
    for (int ni = 0; ni < 4; ++ni)
      bfr[ni] = *(const bf16x8*)(&Bl[(wx * 64 + ni * 16 + l15) * LROW + quad * 8]);
#pragma unroll
    for (int mi = 0; mi < 4; ++mi)
#pragma unroll
      for (int ni = 0; ni < 4; ++ni)
        acc[mi][ni] = __builtin_amdgcn_mfma_f32_16x16x32_bf16(af[mi], bfr[ni], acc[mi][ni], 0, 0, 0);
    __syncthreads();
  }
#pragma unroll
  for (int mi = 0; mi < 4; ++mi) {
    int row0 = m0 + wy * 64 + mi * 16 + quad * 4;
#pragma unroll
    for (int ni = 0; ni < 4; ++ni) {
      int col = n0 + wx * 64 + ni * 16 + l15;
      float bb = BIAS ? bias[col] : 0.f;
#pragma unroll
      for (int r = 0; r < 4; ++r) {
        float v = acc[mi][ni][r] + bb;
        if (RELU) v = fmaxf(v, 0.f);
        int row = row0 + r;
        if (OUTMODE == 2) {
          int b = row >> 10, t = row & (T_ - 1);
          int h = col >> 6, hs = col & 63;
          ((unsigned short*)Cv)[((size_t)((b * H_ + h) * HS_ + hs)) * T_ + t] = f2b(v);
        } else {
          size_t off = (size_t)row * ldc + col;
          if (ACC) v += ((const float*)Cv)[off];
          if (OUTMODE == 1) ((unsigned short*)Cv)[off] = f2b(v);
          else              ((float*)Cv)[off] = v;
        }
      }
    }
  }
}

// ---------------- MFMA flash attention: 64 q-rows per block, 4 waves ----------------
// q,k: bf16 [BT][D]; vt: bf16 [(b*H+h)*HS+hs][T]; o: bf16 [BT][D]
__global__ __launch_bounds__(256) void attn_mfma(const unsigned short* __restrict__ q,
    const unsigned short* __restrict__ k, const unsigned short* __restrict__ vt,
    unsigned short* __restrict__ o) {
  __shared__ unsigned short Pbuf[64 * 72];
  __shared__ float wred[4][64];
  __shared__ float rowm[64], rowl[64], ralpha[64];
  const int qt = (gridDim.x - 1) - blockIdx.x;   // heavy tiles dispatch first
  const int bh = blockIdx.y;
  const int b = bh >> 3, hh = bh & 7;
  const int tid = threadIdx.x;
  const int lane = tid & 63, w = tid >> 6;
  const int l15 = lane & 15, quad = lane >> 4;
  const float scale = 0.044194173824159216f;  // 512^-0.5 (reference scales by D)

  // Q a-frags resident in registers: A[m=l15][k=quad*8..]: rows qt*64+mi*16+l15
  bf16x8 qf[4][2];
#pragma unroll
  for (int mi = 0; mi < 4; ++mi)
#pragma unroll
    for (int c = 0; c < 2; ++c)
      qf[mi][c] = *(const bf16x8*)(q + (size_t)(b * T_ + qt * 64 + mi * 16 + l15) * D_
                                     + hh * HS_ + c * 32 + quad * 8);
  if (tid < 64) { rowm[tid] = -INFINITY; rowl[tid] = 0.f; }
  __syncthreads();

  f32x4 oacc[4];
  const f32x4 z4 = {0.f, 0.f, 0.f, 0.f};
#pragma unroll
  for (int mi = 0; mi < 4; ++mi) oacc[mi] = z4;

  for (int kt = 0; kt <= qt; ++kt) {
    // ---- S = Q @ K^T (wave w owns s-cols w*16..w*16+15) ----
    f32x4 s[4];
#pragma unroll
    for (int mi = 0; mi < 4; ++mi) s[mi] = z4;
#pragma unroll
    for (int c = 0; c < 2; ++c) {
      bf16x8 kf = *(const bf16x8*)(k + (size_t)(b * T_ + kt * 64 + w * 16 + l15) * D_
                                     + hh * HS_ + c * 32 + quad * 8);
#pragma unroll
      for (int mi = 0; mi < 4; ++mi)
        s[mi] = __builtin_amdgcn_mfma_f32_16x16x32_bf16(qf[mi][c], kf, s[mi], 0, 0, 0);
    }
    // ---- scale + causal mask + per-row max partials (16-lane shuffle reduce) ----
    const bool diag = (kt == qt);
#pragma unroll
    for (int mi = 0; mi < 4; ++mi)
#pragma unroll
      for (int r = 0; r < 4; ++r) {
        float v = s[mi][r] * scale;
        if (diag) {
          int gr = mi * 16 + quad * 4 + r, gc = w * 16 + l15;
          if (gc > gr) v = -INFINITY;
        }
        s[mi][r] = v;
        float mx = v;
        mx = fmaxf(mx, __shfl_xor(mx, 1, 64));
        mx = fmaxf(mx, __shfl_xor(mx, 2, 64));
        mx = fmaxf(mx, __shfl_xor(mx, 4, 64));
        mx = fmaxf(mx, __shfl_xor(mx, 8, 64));
        if (l15 == 0) wred[w][mi * 16 + quad * 4 + r] = mx;
      }
    __syncthreads();
    // ---- per-row online-softmax state update ----
    if (tid < 64) {
      float mloc = fmaxf(fmaxf(wred[0][tid], wred[1][tid]), fmaxf(wred[2][tid], wred[3][tid]));
      float mold = rowm[tid];
      float mnew = fmaxf(mold, mloc);
      ralpha[tid] = (mold == -INFINITY) ? 0.f : expf(mold - mnew);
      rowm[tid] = mnew;
    }
    __syncthreads();
    // ---- P = exp(S - m), write bf16 to LDS (A-frag layout), sum partials, rescale O ----
#pragma unroll
    for (int mi = 0; mi < 4; ++mi)
#pragma unroll
      for (int r = 0; r < 4; ++r) {
        int row = mi * 16 + quad * 4 + r;
        float p = expf(s[mi][r] - rowm[row]);
        Pbuf[row * 72 + w * 16 + l15] = f2b(p);
        float sm = p;
        sm += __shfl_xor(sm, 1, 64);
        sm += __shfl_xor(sm, 2, 64);
        sm += __shfl_xor(sm, 4, 64);
        sm += __shfl_xor(sm, 8, 64);
        if (l15 == 0) wred[w][row] = sm;
        oacc[mi][r] *= ralpha[row];
      }
    __syncthreads();
    // ---- row-sum fold + O += P @ V ----
    if (tid < 64)
      rowl[tid] = ralpha[tid] * rowl[tid] +
                  wred[0][tid] + wred[1][tid] + wred[2][tid] + wred[3][tid];
#pragma unroll
    for (int c = 0; c < 2; ++c) {
      bf16x8 vf = *(const bf16x8*)(vt + ((size_t)(bh * HS_ + w * 16 + l15)) * T_
                                      + kt * 64 + c * 32 + quad * 8);
#pragma unroll
      for (int mi = 0; mi < 4; ++mi) {
        bf16x8 pf = *(const bf16x8*)(&Pbuf[(mi * 16 + l15) * 72 + c * 32 + quad * 8]);
        oacc[mi] = __builtin_amdgcn_mfma_f32_16x16x32_bf16(pf, vf, oacc[mi], 0, 0, 0);
      }
    }
    __syncthreads();
  }
  // ---- epilogue: O / rowl, bf16, concat-head layout ----
#pragma unroll
  for (int mi = 0; mi < 4; ++mi)
#pragma unroll
    for (int r = 0; r < 4; ++r) {
      int row = mi * 16 + quad * 4 + r;
      float inv = 1.f / rowl[row];
      o[(size_t)(b * T_ + qt * 64 + row) * D_ + hh * HS_ + w * 16 + l15] =
          f2b(oacc[mi][r] * inv);
    }
}

// ---------------- f32 tiled GEMM (logits only) ----------------
__global__ __launch_bounds__(256) void gemm_f32_kernel(const float* __restrict__ A, int lda,
    const float* __restrict__ Bw, int ldb, const float* __restrict__ bias,
    float* __restrict__ C, int ldc, int K, int N) {
  __shared__ float As[16][64];
  __shared__ float Bs[16][64];
  int n0 = blockIdx.y * 64;
  int nv = N - n0; if (nv > 64) nv = 64;
  int m0 = blockIdx.x * 64;
  const int tid = threadIdx.x;
  const int tx = tid & 15, ty = tid >> 4;
  const int amm = tid >> 2;
  const int akk = (tid & 3) * 4;
  const int bkk = tid >> 4;
  const int bnn = (tid & 15) * 4;
  float acc[4][4] = {};
  for (int k0 = 0; k0 < K; k0 += 16) {
    float4 av = *(const float4*)(A + (size_t)(m0 + amm) * lda + k0 + akk);
    As[akk + 0][amm] = av.x; As[akk + 1][amm] = av.y;
    As[akk + 2][amm] = av.z; As[akk + 3][amm] = av.w;
    if (bnn < nv) {
      float4 bv = *(const float4*)(Bw + (size_t)(k0 + bkk) * ldb + n0 + bnn);
      Bs[bkk][bnn + 0] = bv.x; Bs[bkk][bnn + 1] = bv.y;
      Bs[bkk][bnn + 2] = bv.z; Bs[bkk][bnn + 3] = bv.w;
    } else {
      Bs[bkk][bnn + 0] = 0.f; Bs[bkk][bnn + 1] = 0.f;
      Bs[bkk][bnn + 2] = 0.f; Bs[bkk][bnn + 3] = 0.f;
    }
    __syncthreads();
#pragma unroll
    for (int kk = 0; kk < 16; ++kk) {
      float4 a4 = *(const float4*)(&As[kk][ty * 4]);
      float4 b4 = *(const float4*)(&Bs[kk][tx * 4]);
      float aa[4] = {a4.x, a4.y, a4.z, a4.w};
      float bb[4] = {b4.x, b4.y, b4.z, b4.w};
#pragma unroll
      for (int i = 0; i < 4; ++i)
#pragma unroll
        for (int j = 0; j < 4; ++j)
          acc[i][j] = fmaf(aa[i], bb[j], acc[i][j]);
    }
    __syncthreads();
  }
  if (tx * 4 < nv) {
#pragma unroll
    for (int i = 0; i < 4; ++i) {
      float* cp = C + (size_t)(m0 + ty * 4 + i) * ldc + n0 + tx * 4;
      float4 st = {acc[i][0] + bias[n0 + tx * 4 + 0], acc[i][1] + bias[n0 + tx * 4 + 1],
                   acc[i][2] + bias[n0 + tx * 4 + 2], acc[i][3] + bias[n0 + tx * 4 + 3]};
      *(float4*)cp = st;
    }
  }
}

// ---------------- loss ----------------
__global__ __launch_bounds__(256) void loss_kernel(const float* __restrict__ logits,
    const int* __restrict__ targets, float* __restrict__ loss_acc) {
  int wave = threadIdx.x >> 6, lane = threadIdx.x & 63;
  int r = blockIdx.x * 4 + wave;
  const float* lr = logits + (size_t)r * V_;
  float v0 = lr[lane];
  float v1 = (lane < 32) ? lr[64 + lane] : -INFINITY;
  float mx = fmaxf(v0, v1);
#pragma unroll
  for (int o = 32; o > 0; o >>= 1) mx = fmaxf(mx, __shfl_xor(mx, o, 64));
  float se = expf(v0 - mx) + ((lane < 32) ? expf(v1 - mx) : 0.f);
#pragma unroll
  for (int o = 32; o > 0; o >>= 1) se += __shfl_xor(se, o, 64);
  if (lane == 0) {
    float logZ = mx + logf(se);
    int tg = targets[r];
    if (tg < 0) tg = 0; if (tg > V_ - 1) tg = V_ - 1;
    atomicAdd(loss_acc, logZ - lr[tg]);
  }
}

__global__ void loss_finalize_kernel(const float* __restrict__ acc, float* __restrict__ out) {
  out[(size_t)BT_ * V_] = acc[0] * (1.f / BT_);
}

// ---------------- host ----------------
static void* g_ws_fallback = nullptr;

extern "C" void kernel_launch(void* const* d_in, const int* in_sizes, int n_in,
                              void* d_out, int out_size, void* d_ws, size_t ws_size,
                              hipStream_t stream) {
  const int*   idx     = (const int*)d_in[0];
  const int*   targets = (const int*)d_in[1];
  const float* tok  = (const float*)d_in[2];
  const float* pos  = (const float*)d_in[3];
  const float* Wq   = (const float*)d_in[4];
  const float* Wk   = (const float*)d_in[5];
  const float* Wv   = (const float*)d_in[6];
  const float* Wp   = (const float*)d_in[7];
  const float* bp   = (const float*)d_in[8];
  const float* W1   = (const float*)d_in[9];
  const float* b1   = (const float*)d_in[10];
  const float* W2   = (const float*)d_in[11];
  const float* b2   = (const float*)d_in[12];
  const float* l1s  = (const float*)d_in[13];
  const float* l1b  = (const float*)d_in[14];
  const float* l2s  = (const float*)d_in[15];
  const float* l2b  = (const float*)d_in[16];
  const float* lfs  = (const float*)d_in[17];
  const float* lfb  = (const float*)d_in[18];
  const float* Wout = (const float*)d_in[19];
  const float* bout = (const float*)d_in[20];
  float* out = (float*)d_out;   // f32 logits + f32 loss scalar

  const size_t n_x  = (size_t)BT_ * D_;
  const size_t n_wT = 9437184;   // transposed bf16 weights (f32-equiv)
  // x(f32) + qfinal/q(f32-size dual-use) + k,vt,hb(bf16) + ffb(bf16) + weights + pad
  const size_t need_floats = n_x + n_x + n_x / 2 + n_x / 2 + n_x / 2 +
                             (size_t)BT_ * FF_ / 2 + n_wT + 256;
  const size_t need_bytes  = need_floats * sizeof(float);

  float* ws;
  if (ws_size >= need_bytes) {
    ws = (float*)d_ws;
  } else {
    if (!g_ws_fallback) (void)hipMalloc(&g_ws_fallback, need_bytes);
    ws = (float*)g_ws_fallback;
  }

  size_t off = 0;
  float* x  = ws + off; off += n_x;
  float* qf32 = ws + off; off += n_x;          // bf16 Q buffer; reused as f32 final-LN
  unsigned short* qb = (unsigned short*)qf32;
  unsigned short* kb  = (unsigned short*)(ws + off); off += n_x / 2;
  unsigned short* vtb = (unsigned short*)(ws + off); off += n_x / 2;
  unsigned short* hb  = (unsigned short*)(ws + off); off += n_x / 2;
  unsigned short* ffb = (unsigned short*)(ws + off); off += (size_t)BT_ * FF_ / 2;
  unsigned short* wqT = (unsigned short*)(ws + off);
  unsigned short* wkT = wqT + (size_t)L_ * D_ * D_;
  unsigned short* wvT = wkT + (size_t)L_ * D_ * D_;
  unsigned short* wpT = wvT + (size_t)L_ * D_ * D_;
  unsigned short* w1T = wpT + (size_t)L_ * D_ * D_;
  unsigned short* w2T = w1T + (size_t)L_ * D_ * FF_;
  off += n_wT;
  float* lacc = ws + off;

  zero_kernel<<<1, 1, 0, stream>>>(lacc);
  embed_kernel<<<BT_, 128, 0, stream>>>(idx, tok, pos, x);

  transpose_cvt<<<dim3(2, 16, 48), 256, 0, stream>>>(Wq, wqT, 512, 64, 32768, 32768);
  transpose_cvt<<<dim3(2, 16, 48), 256, 0, stream>>>(Wk, wkT, 512, 64, 32768, 32768);
  transpose_cvt<<<dim3(2, 16, 48), 256, 0, stream>>>(Wv, wvT, 512, 64, 32768, 32768);
  transpose_cvt<<<dim3(16, 16, 6), 256, 0, stream>>>(Wp, wpT, 512, 512, 262144, 262144);
  transpose_cvt<<<dim3(64, 16, 6), 256, 0, stream>>>(W1, w1T, 512, 2048, 1048576, 1048576);
  transpose_cvt<<<dim3(16, 64, 6), 256, 0, stream>>>(W2, w2T, 2048, 512, 1048576, 1048576);

  const dim3 gD(BT_ / 128, D_ / 128);
  const dim3 gF(BT_ / 128, FF_ / 128);

  for (int l = 0; l < L_; ++l) {
    ln_kernel<true><<<BT_ / 4, 256, 0, stream>>>(x, l1s + (size_t)l * D_, l1b + (size_t)l * D_, hb);
    mfma_gemm<false, false, false, 1><<<gD, 256, 0, stream>>>(
        hb, wqT + (size_t)l * D_ * D_, nullptr, qb, D_, D_);
    mfma_gemm<false, false, false, 1><<<gD, 256, 0, stream>>>(
        hb, wkT + (size_t)l * D_ * D_, nullptr, kb, D_, D_);
    mfma_gemm<false, false, false, 2><<<gD, 256, 0, stream>>>(
        hb, wvT + (size_t)l * D_ * D_, nullptr, vtb, D_, D_);
    attn_mfma<<<dim3(T_ / 64, B_ * H_), 256, 0, stream>>>(qb, kb, vtb, hb);
    mfma_gemm<true, false, true, 0><<<gD, 256, 0, stream>>>(
        hb, wpT + (size_t)l * D_ * D_, bp + (size_t)l * D_, x, D_, D_);
    ln_kernel<true><<<BT_ / 4, 256, 0, stream>>>(x, l2s + (size_t)l * D_, l2b + (size_t)l * D_, hb);
    mfma_gemm<false, true, true, 1><<<gF, 256, 0, stream>>>(
        hb, w1T + (size_t)l * D_ * FF_, b1 + (size_t)l * FF_, ffb, D_, FF_);
    mfma_gemm<true, false, true, 0><<<gD, 256, 0, stream>>>(
        ffb, w2T + (size_t)l * FF_ * D_, b2 + (size_t)l * D_, x, FF_, D_);
  }

  ln_kernel<false><<<BT_ / 4, 256, 0, stream>>>(x, lfs, lfb, qf32);
  gemm_f32_kernel<<<dim3(BT_ / 64, 2), 256, 0, stream>>>(
      qf32, D_, Wout, V_, bout, out, V_, D_, V_);
  loss_kernel<<<BT_ / 4, 256, 0, stream>>>(out, targets, lacc);
  loss_finalize_kernel<<<1, 1, 0, stream>>>(lacc, out);
}

// Round 10
// 2349.965 us; speedup vs baseline: 5.9517x; 1.6763x over previous
//
#include <hip/hip_runtime.h>

#define B_  16
#define T_  1024
#define D_  512
#define H_  8
#define L_  6
#define V_  96
#define HS_ 64
#define FF_ 2048
#define BT_ (B_*T_)

typedef __attribute__((ext_vector_type(8))) short bf16x8;
typedef __attribute__((ext_vector_type(4))) float f32x4;

__device__ __forceinline__ unsigned short f2b(float f) {
  unsigned u = __float_as_uint(f);
  unsigned r = (u + 0x7FFFu + ((u >> 16) & 1u)) >> 16;
  return (unsigned short)r;
}

__global__ void zero_kernel(float* p) { p[0] = 0.f; }

// ---------------- embedding ----------------
__global__ __launch_bounds__(128) void embed_kernel(const int* __restrict__ idx,
    const float* __restrict__ tok, const float* __restrict__ pos, float* __restrict__ x) {
  int bt = blockIdx.x;
  int t  = bt & (T_ - 1);
  int id = idx[bt];
  if (id < 0) id = 0; if (id > V_ - 1) id = V_ - 1;
  int d  = threadIdx.x * 4;
  float4 tv = *(const float4*)(tok + (size_t)id * D_ + d);
  float4 pv = *(const float4*)(pos + (size_t)t  * D_ + d);
  float4 o = {tv.x + pv.x, tv.y + pv.y, tv.z + pv.z, tv.w + pv.w};
  *(float4*)(x + (size_t)bt * D_ + d) = o;
}

// ---------------- tiled transpose + f32->bf16: dst[C][R] = src[R][C] ----------------
__global__ __launch_bounds__(256) void transpose_cvt(const float* __restrict__ src,
    unsigned short* __restrict__ dst, int R, int C, long sstride, long dstride) {
  __shared__ float t[32][33];
  const float* s = src + (size_t)blockIdx.z * sstride;
  unsigned short* d = dst + (size_t)blockIdx.z * dstride;
  int r0 = blockIdx.y * 32, c0 = blockIdx.x * 32;
  int tr = threadIdx.x >> 5, tc = threadIdx.x & 31;
#pragma unroll
  for (int i = 0; i < 4; ++i)
    t[tr + i * 8][tc] = s[(size_t)(r0 + tr + i * 8) * C + c0 + tc];
  __syncthreads();
#pragma unroll
  for (int i = 0; i < 4; ++i)
    d[(size_t)(c0 + tr + i * 8) * R + r0 + tc] = f2b(t[tc][tr + i * 8]);
}

// ---------------- layernorm: one wave per row; bf16 or f32 out ----------------
template<bool BF16OUT>
__global__ __launch_bounds__(256) void ln_kernel(const float* __restrict__ x,
    const float* __restrict__ s, const float* __restrict__ b, void* __restrict__ outv) {
  int wave = threadIdx.x >> 6;
  int lane = threadIdx.x & 63;
  int r = blockIdx.x * 4 + wave;
  const float* xr = x + (size_t)r * D_;
  float vals[8];
  float sum = 0.f;
#pragma unroll
  for (int j = 0; j < 8; ++j) { vals[j] = xr[j * 64 + lane]; sum += vals[j]; }
#pragma unroll
  for (int o = 32; o > 0; o >>= 1) sum += __shfl_xor(sum, o, 64);
  float mean = sum * (1.f / D_);
  float vs = 0.f;
#pragma unroll
  for (int j = 0; j < 8; ++j) { float d = vals[j] - mean; vs += d * d; }
#pragma unroll
  for (int o = 32; o > 0; o >>= 1) vs += __shfl_xor(vs, o, 64);
  float rstd = rsqrtf(vs * (1.f / D_) + 1e-5f);
#pragma unroll
  for (int j = 0; j < 8; ++j) {
    int c = j * 64 + lane;
    float v = (vals[j] - mean) * rstd * s[c] + b[c];
    if (BF16OUT) ((unsigned short*)outv)[(size_t)r * D_ + c] = f2b(v);
    else         ((float*)outv)[(size_t)r * D_ + c] = v;
  }
}

// ---------------- bf16 MFMA GEMM: C[M,N] (+)= A[M,K] @ Bt[N,K]^T ----------------
// OUTMODE: 0 = f32 [M][ldc], 1 = bf16 [M][ldc], 2 = bf16 Vt[(b*H+h)*HS+hs][T] (V transpose)
#define LROW 40
template<bool ACC, bool RELU, bool BIAS, int OUTMODE>
__global__ __launch_bounds__(256) void mfma_gemm(
    const unsigned short* __restrict__ A,
    const unsigned short* __restrict__ Bt,
    const float* __restrict__ bias,
    void* __restrict__ Cv,
    int K, int ldc) {
  __shared__ unsigned short Al[128 * LROW];
  __shared__ unsigned short Bl[128 * LROW];
  const int m0 = blockIdx.x * 128, n0 = blockIdx.y * 128;
  const int tid = threadIdx.x;
  const int lane = tid & 63, wave = tid >> 6;
  const int wy = wave >> 1, wx = wave & 1;
  const int l15 = lane & 15, quad = lane >> 4;
  f32x4 acc[4][4];
  const f32x4 z4 = {0.f, 0.f, 0.f, 0.f};
#pragma unroll
  for (int mi = 0; mi < 4; ++mi)
#pragma unroll
    for (int ni = 0; ni < 4; ++ni) acc[mi][ni] = z4;

  for (int k0 = 0; k0 < K; k0 += 32) {
#pragma unroll
    for (int i = 0; i < 2; ++i) {
      int c = tid + 256 * i;
      int row = c >> 2, kc = (c & 3) * 8;
      bf16x8 av = *(const bf16x8*)(A + (size_t)(m0 + row) * K + k0 + kc);
      *(bf16x8*)(&Al[row * LROW + kc]) = av;
      bf16x8 bv = *(const bf16x8*)(Bt + (size_t)(n0 + row) * K + k0 + kc);
      *(bf16x8*)(&Bl[row * LROW + kc]) = bv;
    }
    __syncthreads();
    bf16x8 af[4], bfr[4];
#pragma unroll
    for (int mi = 0; mi < 4; ++mi)
      af[mi] = *(const bf16x8*)(&Al[(wy * 64 + mi * 16 + l15) * LROW + quad * 8]);
#pragma unroll
    for (int ni = 0; ni < 4; ++ni)
      bfr[ni] = *(const bf16x8*)(&Bl[(wx * 64 + ni * 16 + l15) * LROW + quad * 8]);
#pragma unroll
    for (int mi = 0; mi < 4; ++mi)
#pragma unroll
      for (int ni = 0; ni < 4; ++ni)
        acc[mi][ni] = __builtin_amdgcn_mfma_f32_16x16x32_bf16(af[mi], bfr[ni], acc[mi][ni], 0, 0, 0);
    __syncthreads();
  }
#pragma unroll
  for (int mi = 0; mi < 4; ++mi) {
    int row0 = m0 + wy * 64 + mi * 16 + quad * 4;
#pragma unroll
    for (int ni = 0; ni < 4; ++ni) {
      int col = n0 + wx * 64 + ni * 16 + l15;
      float bb = BIAS ? bias[col] : 0.f;
#pragma unroll
      for (int r = 0; r < 4; ++r) {
        float v = acc[mi][ni][r] + bb;
        if (RELU) v = fmaxf(v, 0.f);
        int row = row0 + r;
        if (OUTMODE == 2) {
          int b = row >> 10, t = row & (T_ - 1);
          int h = col >> 6, hs = col & 63;
          ((unsigned short*)Cv)[((size_t)((b * H_ + h) * HS_ + hs)) * T_ + t] = f2b(v);
        } else {
          size_t off = (size_t)row * ldc + col;
          if (ACC) v += ((const float*)Cv)[off];
          if (OUTMODE == 1) ((unsigned short*)Cv)[off] = f2b(v);
          else              ((float*)Cv)[off] = v;
        }
      }
    }
  }
}

// ---------------- MFMA flash attention, no-max softmax ----------------
// Scores are tiny by construction (|s*scale| < ~1), so softmax needs no max
// subtraction: P = exp2(S*scale*log2e), l = P@1 accumulated on the MFMA pipe
// (all-ones B-frag -> row sums land in the same C-layout slots as O's rows).
// q,k: bf16 [BT][D]; vt: bf16 [(b*H+h)*HS+hs][T]; o: bf16 [BT][D]
#define PSTR 72
__global__ __launch_bounds__(256) void attn_mfma(const unsigned short* __restrict__ q,
    const unsigned short* __restrict__ k, const unsigned short* __restrict__ vt,
    unsigned short* __restrict__ o) {
  __shared__ unsigned short Pbuf[2][64 * PSTR];
  const int qt = (gridDim.x - 1) - blockIdx.x;   // heavy tiles dispatch first
  const int bh = blockIdx.y;
  const int b = bh >> 3, hh = bh & 7;
  const int tid = threadIdx.x;
  const int lane = tid & 63, w = tid >> 6;
  const int l15 = lane & 15, quad = lane >> 4;
  const float CEXP = 0.044194173824159216f * 1.4426950408889634f;  // scale*log2(e)

  // Q a-frags resident: A[m=l15][k=quad*8..], rows qt*64+mi*16+l15
  bf16x8 qf[4][2];
#pragma unroll
  for (int mi = 0; mi < 4; ++mi)
#pragma unroll
    for (int c = 0; c < 2; ++c)
      qf[mi][c] = *(const bf16x8*)(q + (size_t)(b * T_ + qt * 64 + mi * 16 + l15) * D_
                                     + hh * HS_ + c * 32 + quad * 8);

  const short one_bf = (short)0x3F80;
  bf16x8 ones = {one_bf, one_bf, one_bf, one_bf, one_bf, one_bf, one_bf, one_bf};

  f32x4 oacc[4], lacc[4];
  const f32x4 z4 = {0.f, 0.f, 0.f, 0.f};
#pragma unroll
  for (int mi = 0; mi < 4; ++mi) { oacc[mi] = z4; lacc[mi] = z4; }

  for (int kt = 0; kt <= qt; ++kt) {
    // ---- S = Q @ K^T (wave w owns s-cols w*16..w*16+15) ----
    f32x4 s[4];
#pragma unroll
    for (int mi = 0; mi < 4; ++mi) s[mi] = z4;
#pragma unroll
    for (int c = 0; c < 2; ++c) {
      bf16x8 kf = *(const bf16x8*)(k + (size_t)(b * T_ + kt * 64 + w * 16 + l15) * D_
                                     + hh * HS_ + c * 32 + quad * 8);
#pragma unroll
      for (int mi = 0; mi < 4; ++mi)
        s[mi] = __builtin_amdgcn_mfma_f32_16x16x32_bf16(qf[mi][c], kf, s[mi], 0, 0, 0);
    }
    // ---- P = exp2(S*CEXP) (masked on diag), bf16 into LDS (A-frag layout) ----
    unsigned short* pb = Pbuf[kt & 1];
    if (kt == qt) {
#pragma unroll
      for (int mi = 0; mi < 4; ++mi)
#pragma unroll
        for (int r = 0; r < 4; ++r) {
          int row = mi * 16 + quad * 4 + r;
          int gc = w * 16 + l15;
          float p = (gc > row) ? 0.f : exp2f(s[mi][r] * CEXP);
          pb[row * PSTR + gc] = f2b(p);
        }
    } else {
#pragma unroll
      for (int mi = 0; mi < 4; ++mi)
#pragma unroll
        for (int r = 0; r < 4; ++r) {
          int row = mi * 16 + quad * 4 + r;
          pb[row * PSTR + w * 16 + l15] = f2b(exp2f(s[mi][r] * CEXP));
        }
    }
    __syncthreads();
    // ---- O += P @ V ; l += P @ 1 (both on MFMA pipe) ----
#pragma unroll
    for (int c = 0; c < 2; ++c) {
      bf16x8 vf = *(const bf16x8*)(vt + ((size_t)(bh * HS_ + w * 16 + l15)) * T_
                                      + kt * 64 + c * 32 + quad * 8);
#pragma unroll
      for (int mi = 0; mi < 4; ++mi) {
        bf16x8 pf = *(const bf16x8*)(&pb[(mi * 16 + l15) * PSTR + c * 32 + quad * 8]);
        oacc[mi] = __builtin_amdgcn_mfma_f32_16x16x32_bf16(pf, vf, oacc[mi], 0, 0, 0);
        lacc[mi] = __builtin_amdgcn_mfma_f32_16x16x32_bf16(pf, ones, lacc[mi], 0, 0, 0);
      }
    }
    // next iteration writes the other Pbuf half: one barrier per k-tile suffices
  }
  // ---- epilogue: O / l, bf16, concat-head layout ----
#pragma unroll
  for (int mi = 0; mi < 4; ++mi)
#pragma unroll
    for (int r = 0; r < 4; ++r) {
      int row = mi * 16 + quad * 4 + r;
      float inv = 1.f / lacc[mi][r];
      o[(size_t)(b * T_ + qt * 64 + row) * D_ + hh * HS_ + w * 16 + l15] =
          f2b(oacc[mi][r] * inv);
    }
}

// ---------------- f32 tiled GEMM (logits only) ----------------
__global__ __launch_bounds__(256) void gemm_f32_kernel(const float* __restrict__ A, int lda,
    const float* __restrict__ Bw, int ldb, const float* __restrict__ bias,
    float* __restrict__ C, int ldc, int K, int N) {
  __shared__ float As[16][64];
  __shared__ float Bs[16][64];
  int n0 = blockIdx.y * 64;
  int nv = N - n0; if (nv > 64) nv = 64;
  int m0 = blockIdx.x * 64;
  const int tid = threadIdx.x;
  const int tx = tid & 15, ty = tid >> 4;
  const int amm = tid >> 2;
  const int akk = (tid & 3) * 4;
  const int bkk = tid >> 4;
  const int bnn = (tid & 15) * 4;
  float acc[4][4] = {};
  for (int k0 = 0; k0 < K; k0 += 16) {
    float4 av = *(const float4*)(A + (size_t)(m0 + amm) * lda + k0 + akk);
    As[akk + 0][amm] = av.x; As[akk + 1][amm] = av.y;
    As[akk + 2][amm] = av.z; As[akk + 3][amm] = av.w;
    if (bnn < nv) {
      float4 bv = *(const float4*)(Bw + (size_t)(k0 + bkk) * ldb + n0 + bnn);
      Bs[bkk][bnn + 0] = bv.x; Bs[bkk][bnn + 1] = bv.y;
      Bs[bkk][bnn + 2] = bv.z; Bs[bkk][bnn + 3] = bv.w;
    } else {
      Bs[bkk][bnn + 0] = 0.f; Bs[bkk][bnn + 1] = 0.f;
      Bs[bkk][bnn + 2] = 0.f; Bs[bkk][bnn + 3] = 0.f;
    }
    __syncthreads();
#pragma unroll
    for (int kk = 0; kk < 16; ++kk) {
      float4 a4 = *(const float4*)(&As[kk][ty * 4]);
      float4 b4 = *(const float4*)(&Bs[kk][tx * 4]);
      float aa[4] = {a4.x, a4.y, a4.z, a4.w};
      float bb[4] = {b4.x, b4.y, b4.z, b4.w};
#pragma unroll
      for (int i = 0; i < 4; ++i)
#pragma unroll
        for (int j = 0; j < 4; ++j)
          acc[i][j] = fmaf(aa[i], bb[j], acc[i][j]);
    }
    __syncthreads();
  }
  if (tx * 4 < nv) {
#pragma unroll
    for (int i = 0; i < 4; ++i) {
      float* cp = C + (size_t)(m0 + ty * 4 + i) * ldc + n0 + tx * 4;
      float4 st = {acc[i][0] + bias[n0 + tx * 4 + 0], acc[i][1] + bias[n0 + tx * 4 + 1],
                   acc[i][2] + bias[n0 + tx * 4 + 2], acc[i][3] + bias[n0 + tx * 4 + 3]};
      *(float4*)cp = st;
    }
  }
}

// ---------------- loss ----------------
__global__ __launch_bounds__(256) void loss_kernel(const float* __restrict__ logits,
    const int* __restrict__ targets, float* __restrict__ loss_acc) {
  int wave = threadIdx.x >> 6, lane = threadIdx.x & 63;
  int r = blockIdx.x * 4 + wave;
  const float* lr = logits + (size_t)r * V_;
  float v0 = lr[lane];
  float v1 = (lane < 32) ? lr[64 + lane] : -INFINITY;
  float mx = fmaxf(v0, v1);
#pragma unroll
  for (int o = 32; o > 0; o >>= 1) mx = fmaxf(mx, __shfl_xor(mx, o, 64));
  float se = expf(v0 - mx) + ((lane < 32) ? expf(v1 - mx) : 0.f);
#pragma unroll
  for (int o = 32; o > 0; o >>= 1) se += __shfl_xor(se, o, 64);
  if (lane == 0) {
    float logZ = mx + logf(se);
    int tg = targets[r];
    if (tg < 0) tg = 0; if (tg > V_ - 1) tg = V_ - 1;
    atomicAdd(loss_acc, logZ - lr[tg]);
  }
}

__global__ void loss_finalize_kernel(const float* __restrict__ acc, float* __restrict__ out) {
  out[(size_t)BT_ * V_] = acc[0] * (1.f / BT_);
}

// ---------------- host ----------------
static void* g_ws_fallback = nullptr;

extern "C" void kernel_launch(void* const* d_in, const int* in_sizes, int n_in,
                              void* d_out, int out_size, void* d_ws, size_t ws_size,
                              hipStream_t stream) {
  const int*   idx     = (const int*)d_in[0];
  const int*   targets = (const int*)d_in[1];
  const float* tok  = (const float*)d_in[2];
  const float* pos  = (const float*)d_in[3];
  const float* Wq   = (const float*)d_in[4];
  const float* Wk   = (const float*)d_in[5];
  const float* Wv   = (const float*)d_in[6];
  const float* Wp   = (const float*)d_in[7];
  const float* bp   = (const float*)d_in[8];
  const float* W1   = (const float*)d_in[9];
  const float* b1   = (const float*)d_in[10];
  const float* W2   = (const float*)d_in[11];
  const float* b2   = (const float*)d_in[12];
  const float* l1s  = (const float*)d_in[13];
  const float* l1b  = (const float*)d_in[14];
  const float* l2s  = (const float*)d_in[15];
  const float* l2b  = (const float*)d_in[16];
  const float* lfs  = (const float*)d_in[17];
  const float* lfb  = (const float*)d_in[18];
  const float* Wout = (const float*)d_in[19];
  const float* bout = (const float*)d_in[20];
  float* out = (float*)d_out;   // f32 logits + f32 loss scalar

  const size_t n_x  = (size_t)BT_ * D_;
  const size_t n_wT = 9437184;   // transposed bf16 weights (f32-equiv)
  const size_t need_floats = n_x + n_x + n_x / 2 + n_x / 2 + n_x / 2 +
                             (size_t)BT_ * FF_ / 2 + n_wT + 256;
  const size_t need_bytes  = need_floats * sizeof(float);

  float* ws;
  if (ws_size >= need_bytes) {
    ws = (float*)d_ws;
  } else {
    if (!g_ws_fallback) (void)hipMalloc(&g_ws_fallback, need_bytes);
    ws = (float*)g_ws_fallback;
  }

  size_t off = 0;
  float* x  = ws + off; off += n_x;
  float* qf32 = ws + off; off += n_x;          // bf16 Q buffer; reused as f32 final-LN
  unsigned short* qb = (unsigned short*)qf32;
  unsigned short* kb  = (unsigned short*)(ws + off); off += n_x / 2;
  unsigned short* vtb = (unsigned short*)(ws + off); off += n_x / 2;
  unsigned short* hb  = (unsigned short*)(ws + off); off += n_x / 2;
  unsigned short* ffb = (unsigned short*)(ws + off); off += (size_t)BT_ * FF_ / 2;
  unsigned short* wqT = (unsigned short*)(ws + off);
  unsigned short* wkT = wqT + (size_t)L_ * D_ * D_;
  unsigned short* wvT = wkT + (size_t)L_ * D_ * D_;
  unsigned short* wpT = wvT + (size_t)L_ * D_ * D_;
  unsigned short* w1T = wpT + (size_t)L_ * D_ * D_;
  unsigned short* w2T = w1T + (size_t)L_ * D_ * FF_;
  off += n_wT;
  float* lacc = ws + off;

  zero_kernel<<<1, 1, 0, stream>>>(lacc);
  embed_kernel<<<BT_, 128, 0, stream>>>(idx, tok, pos, x);

  transpose_cvt<<<dim3(2, 16, 48), 256, 0, stream>>>(Wq, wqT, 512, 64, 32768, 32768);
  transpose_cvt<<<dim3(2, 16, 48), 256, 0, stream>>>(Wk, wkT, 512, 64, 32768, 32768);
  transpose_cvt<<<dim3(2, 16, 48), 256, 0, stream>>>(Wv, wvT, 512, 64, 32768, 32768);
  transpose_cvt<<<dim3(16, 16, 6), 256, 0, stream>>>(Wp, wpT, 512, 512, 262144, 262144);
  transpose_cvt<<<dim3(64, 16, 6), 256, 0, stream>>>(W1, w1T, 512, 2048, 1048576, 1048576);
  transpose_cvt<<<dim3(16, 64, 6), 256, 0, stream>>>(W2, w2T, 2048, 512, 1048576, 1048576);

  const dim3 gD(BT_ / 128, D_ / 128);
  const dim3 gF(BT_ / 128, FF_ / 128);

  for (int l = 0; l < L_; ++l) {
    ln_kernel<true><<<BT_ / 4, 256, 0, stream>>>(x, l1s + (size_t)l * D_, l1b + (size_t)l * D_, hb);
    mfma_gemm<false, false, false, 1><<<gD, 256, 0, stream>>>(
        hb, wqT + (size_t)l * D_ * D_, nullptr, qb, D_, D_);
    mfma_gemm<false, false, false, 1><<<gD, 256, 0, stream>>>(
        hb, wkT + (size_t)l * D_ * D_, nullptr, kb, D_, D_);
    mfma_gemm<false, false, false, 2><<<gD, 256, 0, stream>>>(
        hb, wvT + (size_t)l * D_ * D_, nullptr, vtb, D_, D_);
    attn_mfma<<<dim3(T_ / 64, B_ * H_), 256, 0, stream>>>(qb, kb, vtb, hb);
    mfma_gemm<true, false, true, 0><<<gD, 256, 0, stream>>>(
        hb, wpT + (size_t)l * D_ * D_, bp + (size_t)l * D_, x, D_, D_);
    ln_kernel<true><<<BT_ / 4, 256, 0, stream>>>(x, l2s + (size_t)l * D_, l2b + (size_t)l * D_, hb);
    mfma_gemm<false, true, true, 1><<<gF, 256, 0, stream>>>(
        hb, w1T + (size_t)l * D_ * FF_, b1 + (size_t)l * FF_, ffb, D_, FF_);
    mfma_gemm<true, false, true, 0><<<gD, 256, 0, stream>>>(
        ffb, w2T + (size_t)l * FF_ * D_, b2 + (size_t)l * D_, x, FF_, D_);
  }

  ln_kernel<false><<<BT_ / 4, 256, 0, stream>>>(x, lfs, lfb, qf32);
  gemm_f32_kernel<<<dim3(BT_ / 64, 2), 256, 0, stream>>>(
      qf32, D_, Wout, V_, bout, out, V_, D_, V_);
  loss_kernel<<<BT_ / 4, 256, 0, stream>>>(out, targets, lacc);
  loss_finalize_kernel<<<1, 1, 0, stream>>>(lacc, out);
}

// Round 11
// 2218.334 us; speedup vs baseline: 6.3049x; 1.0593x over previous
//
#include <hip/hip_runtime.h>

#define B_  16
#define T_  1024
#define D_  512
#define H_  8
#define L_  6
#define V_  96
#define HS_ 64
#define FF_ 2048
#define BT_ (B_*T_)

typedef __attribute__((ext_vector_type(8))) short bf16x8;
typedef __attribute__((ext_vector_type(4))) float f32x4;

__device__ __forceinline__ unsigned short f2b(float f) {
  unsigned u = __float_as_uint(f);
  unsigned r = (u + 0x7FFFu + ((u >> 16) & 1u)) >> 16;
  return (unsigned short)r;
}

__global__ void zero_kernel(float* p) { p[0] = 0.f; }

// ---------------- embedding ----------------
__global__ __launch_bounds__(128) void embed_kernel(const int* __restrict__ idx,
    const float* __restrict__ tok, const float* __restrict__ pos, float* __restrict__ x) {
  int bt = blockIdx.x;
  int t  = bt & (T_ - 1);
  int id = idx[bt];
  if (id < 0) id = 0; if (id > V_ - 1) id = V_ - 1;
  int d  = threadIdx.x * 4;
  float4 tv = *(const float4*)(tok + (size_t)id * D_ + d);
  float4 pv = *(const float4*)(pos + (size_t)t  * D_ + d);
  float4 o = {tv.x + pv.x, tv.y + pv.y, tv.z + pv.z, tv.w + pv.w};
  *(float4*)(x + (size_t)bt * D_ + d) = o;
}

// ---------------- tiled transpose + f32->bf16: dst[C][R] = src[R][C] ----------------
__global__ __launch_bounds__(256) void transpose_cvt(const float* __restrict__ src,
    unsigned short* __restrict__ dst, int R, int C, long sstride, long dstride) {
  __shared__ float t[32][33];
  const float* s = src + (size_t)blockIdx.z * sstride;
  unsigned short* d = dst + (size_t)blockIdx.z * dstride;
  int r0 = blockIdx.y * 32, c0 = blockIdx.x * 32;
  int tr = threadIdx.x >> 5, tc = threadIdx.x & 31;
#pragma unroll
  for (int i = 0; i < 4; ++i)
    t[tr + i * 8][tc] = s[(size_t)(r0 + tr + i * 8) * C + c0 + tc];
  __syncthreads();
#pragma unroll
  for (int i = 0; i < 4; ++i)
    d[(size_t)(c0 + tr + i * 8) * R + r0 + tc] = f2b(t[tc][tr + i * 8]);
}

// ---------------- layernorm: one wave per row; bf16 or f32 out ----------------
template<bool BF16OUT>
__global__ __launch_bounds__(256) void ln_kernel(const float* __restrict__ x,
    const float* __restrict__ s, const float* __restrict__ b, void* __restrict__ outv) {
  int wave = threadIdx.x >> 6;
  int lane = threadIdx.x & 63;
  int r = blockIdx.x * 4 + wave;
  const float* xr = x + (size_t)r * D_;
  float vals[8];
  float sum = 0.f;
#pragma unroll
  for (int j = 0; j < 8; ++j) { vals[j] = xr[j * 64 + lane]; sum += vals[j]; }
#pragma unroll
  for (int o = 32; o > 0; o >>= 1) sum += __shfl_xor(sum, o, 64);
  float mean = sum * (1.f / D_);
  float vs = 0.f;
#pragma unroll
  for (int j = 0; j < 8; ++j) { float d = vals[j] - mean; vs += d * d; }
#pragma unroll
  for (int o = 32; o > 0; o >>= 1) vs += __shfl_xor(vs, o, 64);
  float rstd = rsqrtf(vs * (1.f / D_) + 1e-5f);
#pragma unroll
  for (int j = 0; j < 8; ++j) {
    int c = j * 64 + lane;
    float v = (vals[j] - mean) * rstd * s[c] + b[c];
    if (BF16OUT) ((unsigned short*)outv)[(size_t)r * D_ + c] = f2b(v);
    else         ((float*)outv)[(size_t)r * D_ + c] = v;
  }
}

// ---------------- bf16 MFMA GEMM: C[M,N] (+)= A[M,K] @ Bt[N,K]^T ----------------
// OUTMODE: 0 = f32 [M][ldc], 1 = bf16 [M][ldc], 2 = bf16 Vt[(b*H+h)*HS+hs][T] (V transpose)
#define LROW 40
template<bool ACC, bool RELU, bool BIAS, int OUTMODE>
__global__ __launch_bounds__(256) void mfma_gemm(
    const unsigned short* __restrict__ A,
    const unsigned short* __restrict__ Bt,
    const float* __restrict__ bias,
    void* __restrict__ Cv,
    int K, int ldc) {
  __shared__ unsigned short Al[128 * LROW];
  __shared__ unsigned short Bl[128 * LROW];
  const int m0 = blockIdx.x * 128, n0 = blockIdx.y * 128;
  const int tid = threadIdx.x;
  const int lane = tid & 63, wave = tid >> 6;
  const int wy = wave >> 1, wx = wave & 1;
  const int l15 = lane & 15, quad = lane >> 4;
  f32x4 acc[4][4];
  const f32x4 z4 = {0.f, 0.f, 0.f, 0.f};
#pragma unroll
  for (int mi = 0; mi < 4; ++mi)
#pragma unroll
    for (int ni = 0; ni < 4; ++ni) acc[mi][ni] = z4;

  for (int k0 = 0; k0 < K; k0 += 32) {
#pragma unroll
    for (int i = 0; i < 2; ++i) {
      int c = tid + 256 * i;
      int row = c >> 2, kc = (c & 3) * 8;
      bf16x8 av = *(const bf16x8*)(A + (size_t)(m0 + row) * K + k0 + kc);
      *(bf16x8*)(&Al[row * LROW + kc]) = av;
      bf16x8 bv = *(const bf16x8*)(Bt + (size_t)(n0 + row) * K + k0 + kc);
      *(bf16x8*)(&Bl[row * LROW + kc]) = bv;
    }
    __syncthreads();
    bf16x8 af[4], bfr[4];
#pragma unroll
    for (int mi = 0; mi < 4; ++mi)
      af[mi] = *(const bf16x8*)(&Al[(wy * 64 + mi * 16 + l15) * LROW + quad * 8]);
#pragma unroll
    for (int ni = 0; ni < 4; ++ni)
      bfr[ni] = *(const bf16x8*)(&Bl[(wx * 64 + ni * 16 + l15) * LROW + quad * 8]);
#pragma unroll
    for (int mi = 0; mi < 4; ++mi)
#pragma unroll
      for (int ni = 0; ni < 4; ++ni)
        acc[mi][ni] = __builtin_amdgcn_mfma_f32_16x16x32_bf16(af[mi], bfr[ni], acc[mi][ni], 0, 0, 0);
    __syncthreads();
  }
#pragma unroll
  for (int mi = 0; mi < 4; ++mi) {
    int row0 = m0 + wy * 64 + mi * 16 + quad * 4;
#pragma unroll
    for (int ni = 0; ni < 4; ++ni) {
      int col = n0 + wx * 64 + ni * 16 + l15;
      float bb = BIAS ? bias[col] : 0.f;
#pragma unroll
      for (int r = 0; r < 4; ++r) {
        float v = acc[mi][ni][r] + bb;
        if (RELU) v = fmaxf(v, 0.f);
        int row = row0 + r;
        if (OUTMODE == 2) {
          int b = row >> 10, t = row & (T_ - 1);
          int h = col >> 6, hs = col & 63;
          ((unsigned short*)Cv)[((size_t)((b * H_ + h) * HS_ + hs)) * T_ + t] = f2b(v);
        } else {
          size_t off = (size_t)row * ldc + col;
          if (ACC) v += ((const float*)Cv)[off];
          if (OUTMODE == 1) ((unsigned short*)Cv)[off] = f2b(v);
          else              ((float*)Cv)[off] = v;
        }
      }
    }
  }
}

// ---------------- MFMA flash attention, no-max softmax ----------------
#define PSTR 72
__global__ __launch_bounds__(256) void attn_mfma(const unsigned short* __restrict__ q,
    const unsigned short* __restrict__ k, const unsigned short* __restrict__ vt,
    unsigned short* __restrict__ o) {
  __shared__ unsigned short Pbuf[2][64 * PSTR];
  const int qt = (gridDim.x - 1) - blockIdx.x;   // heavy tiles dispatch first
  const int bh = blockIdx.y;
  const int b = bh >> 3, hh = bh & 7;
  const int tid = threadIdx.x;
  const int lane = tid & 63, w = tid >> 6;
  const int l15 = lane & 15, quad = lane >> 4;
  const float CEXP = 0.044194173824159216f * 1.4426950408889634f;  // scale*log2(e)

  bf16x8 qf[4][2];
#pragma unroll
  for (int mi = 0; mi < 4; ++mi)
#pragma unroll
    for (int c = 0; c < 2; ++c)
      qf[mi][c] = *(const bf16x8*)(q + (size_t)(b * T_ + qt * 64 + mi * 16 + l15) * D_
                                     + hh * HS_ + c * 32 + quad * 8);

  const short one_bf = (short)0x3F80;
  bf16x8 ones = {one_bf, one_bf, one_bf, one_bf, one_bf, one_bf, one_bf, one_bf};

  f32x4 oacc[4], lacc[4];
  const f32x4 z4 = {0.f, 0.f, 0.f, 0.f};
#pragma unroll
  for (int mi = 0; mi < 4; ++mi) { oacc[mi] = z4; lacc[mi] = z4; }

  for (int kt = 0; kt <= qt; ++kt) {
    f32x4 s[4];
#pragma unroll
    for (int mi = 0; mi < 4; ++mi) s[mi] = z4;
#pragma unroll
    for (int c = 0; c < 2; ++c) {
      bf16x8 kf = *(const bf16x8*)(k + (size_t)(b * T_ + kt * 64 + w * 16 + l15) * D_
                                     + hh * HS_ + c * 32 + quad * 8);
#pragma unroll
      for (int mi = 0; mi < 4; ++mi)
        s[mi] = __builtin_amdgcn_mfma_f32_16x16x32_bf16(qf[mi][c], kf, s[mi], 0, 0, 0);
    }
    unsigned short* pb = Pbuf[kt & 1];
    if (kt == qt) {
#pragma unroll
      for (int mi = 0; mi < 4; ++mi)
#pragma unroll
        for (int r = 0; r < 4; ++r) {
          int row = mi * 16 + quad * 4 + r;
          int gc = w * 16 + l15;
          float p = (gc > row) ? 0.f : exp2f(s[mi][r] * CEXP);
          pb[row * PSTR + gc] = f2b(p);
        }
    } else {
#pragma unroll
      for (int mi = 0; mi < 4; ++mi)
#pragma unroll
        for (int r = 0; r < 4; ++r) {
          int row = mi * 16 + quad * 4 + r;
          pb[row * PSTR + w * 16 + l15] = f2b(exp2f(s[mi][r] * CEXP));
        }
    }
    __syncthreads();
#pragma unroll
    for (int c = 0; c < 2; ++c) {
      bf16x8 vf = *(const bf16x8*)(vt + ((size_t)(bh * HS_ + w * 16 + l15)) * T_
                                      + kt * 64 + c * 32 + quad * 8);
#pragma unroll
      for (int mi = 0; mi < 4; ++mi) {
        bf16x8 pf = *(const bf16x8*)(&pb[(mi * 16 + l15) * PSTR + c * 32 + quad * 8]);
        oacc[mi] = __builtin_amdgcn_mfma_f32_16x16x32_bf16(pf, vf, oacc[mi], 0, 0, 0);
        lacc[mi] = __builtin_amdgcn_mfma_f32_16x16x32_bf16(pf, ones, lacc[mi], 0, 0, 0);
      }
    }
  }
#pragma unroll
  for (int mi = 0; mi < 4; ++mi)
#pragma unroll
    for (int r = 0; r < 4; ++r) {
      int row = mi * 16 + quad * 4 + r;
      float inv = 1.f / lacc[mi][r];
      o[(size_t)(b * T_ + qt * 64 + row) * D_ + hh * HS_ + w * 16 + l15] =
          f2b(oacc[mi][r] * inv);
    }
}

// ---------------- f32 tiled GEMM (logits only) ----------------
__global__ __launch_bounds__(256) void gemm_f32_kernel(const float* __restrict__ A, int lda,
    const float* __restrict__ Bw, int ldb, const float* __restrict__ bias,
    float* __restrict__ C, int ldc, int K, int N) {
  __shared__ float As[16][64];
  __shared__ float Bs[16][64];
  int n0 = blockIdx.y * 64;
  int nv = N - n0; if (nv > 64) nv = 64;
  int m0 = blockIdx.x * 64;
  const int tid = threadIdx.x;
  const int tx = tid & 15, ty = tid >> 4;
  const int amm = tid >> 2;
  const int akk = (tid & 3) * 4;
  const int bkk = tid >> 4;
  const int bnn = (tid & 15) * 4;
  float acc[4][4] = {};
  for (int k0 = 0; k0 < K; k0 += 16) {
    float4 av = *(const float4*)(A + (size_t)(m0 + amm) * lda + k0 + akk);
    As[akk + 0][amm] = av.x; As[akk + 1][amm] = av.y;
    As[akk + 2][amm] = av.z; As[akk + 3][amm] = av.w;
    if (bnn < nv) {
      float4 bv = *(const float4*)(Bw + (size_t)(k0 + bkk) * ldb + n0 + bnn);
      Bs[bkk][bnn + 0] = bv.x; Bs[bkk][bnn + 1] = bv.y;
      Bs[bkk][bnn + 2] = bv.z; Bs[bkk][bnn + 3] = bv.w;
    } else {
      Bs[bkk][bnn + 0] = 0.f; Bs[bkk][bnn + 1] = 0.f;
      Bs[bkk][bnn + 2] = 0.f; Bs[bkk][bnn + 3] = 0.f;
    }
    __syncthreads();
#pragma unroll
    for (int kk = 0; kk < 16; ++kk) {
      float4 a4 = *(const float4*)(&As[kk][ty * 4]);
      float4 b4 = *(const float4*)(&Bs[kk][tx * 4]);
      float aa[4] = {a4.x, a4.y, a4.z, a4.w};
      float bb[4] = {b4.x, b4.y, b4.z, b4.w};
#pragma unroll
      for (int i = 0; i < 4; ++i)
#pragma unroll
        for (int j = 0; j < 4; ++j)
          acc[i][j] = fmaf(aa[i], bb[j], acc[i][j]);
    }
    __syncthreads();
  }
  if (tx * 4 < nv) {
#pragma unroll
    for (int i = 0; i < 4; ++i) {
      float* cp = C + (size_t)(m0 + ty * 4 + i) * ldc + n0 + tx * 4;
      float4 st = {acc[i][0] + bias[n0 + tx * 4 + 0], acc[i][1] + bias[n0 + tx * 4 + 1],
                   acc[i][2] + bias[n0 + tx * 4 + 2], acc[i][3] + bias[n0 + tx * 4 + 3]};
      *(float4*)cp = st;
    }
  }
}

// ---------------- loss: hierarchical reduction, one atomic per block ----------------
// 64 blocks x 4 waves; each wave grid-strides over rows. G12: per-wave register
// accumulation -> LDS fold -> single atomicAdd per block (64 total, was 16384).
__global__ __launch_bounds__(256) void loss_kernel(const float* __restrict__ logits,
    const int* __restrict__ targets, float* __restrict__ loss_acc) {
  __shared__ float wsum[4];
  int wave = threadIdx.x >> 6, lane = threadIdx.x & 63;
  float local = 0.f;
  for (int r = blockIdx.x * 4 + wave; r < BT_; r += gridDim.x * 4) {
    const float* lr = logits + (size_t)r * V_;
    float v0 = lr[lane];
    float v1 = (lane < 32) ? lr[64 + lane] : -INFINITY;
    float mx = fmaxf(v0, v1);
#pragma unroll
    for (int o = 32; o > 0; o >>= 1) mx = fmaxf(mx, __shfl_xor(mx, o, 64));
    float se = expf(v0 - mx) + ((lane < 32) ? expf(v1 - mx) : 0.f);
#pragma unroll
    for (int o = 32; o > 0; o >>= 1) se += __shfl_xor(se, o, 64);
    if (lane == 0) {
      int tg = targets[r];
      if (tg < 0) tg = 0; if (tg > V_ - 1) tg = V_ - 1;
      local += (mx + logf(se)) - lr[tg];
    }
  }
  if (lane == 0) wsum[wave] = local;
  __syncthreads();
  if (threadIdx.x == 0)
    atomicAdd(loss_acc, wsum[0] + wsum[1] + wsum[2] + wsum[3]);
}

__global__ void loss_finalize_kernel(const float* __restrict__ acc, float* __restrict__ out) {
  out[(size_t)BT_ * V_] = acc[0] * (1.f / BT_);
}

// ---------------- host ----------------
static void* g_ws_fallback = nullptr;

extern "C" void kernel_launch(void* const* d_in, const int* in_sizes, int n_in,
                              void* d_out, int out_size, void* d_ws, size_t ws_size,
                              hipStream_t stream) {
  const int*   idx     = (const int*)d_in[0];
  const int*   targets = (const int*)d_in[1];
  const float* tok  = (const float*)d_in[2];
  const float* pos  = (const float*)d_in[3];
  const float* Wq   = (const float*)d_in[4];
  const float* Wk   = (const float*)d_in[5];
  const float* Wv   = (const float*)d_in[6];
  const float* Wp   = (const float*)d_in[7];
  const float* bp   = (const float*)d_in[8];
  const float* W1   = (const float*)d_in[9];
  const float* b1   = (const float*)d_in[10];
  const float* W2   = (const float*)d_in[11];
  const float* b2   = (const float*)d_in[12];
  const float* l1s  = (const float*)d_in[13];
  const float* l1b  = (const float*)d_in[14];
  const float* l2s  = (const float*)d_in[15];
  const float* l2b  = (const float*)d_in[16];
  const float* lfs  = (const float*)d_in[17];
  const float* lfb  = (const float*)d_in[18];
  const float* Wout = (const float*)d_in[19];
  const float* bout = (const float*)d_in[20];
  float* out = (float*)d_out;   // f32 logits + f32 loss scalar

  const size_t n_x  = (size_t)BT_ * D_;
  const size_t n_wT = 9437184;   // transposed bf16 weights (f32-equiv)
  const size_t need_floats = n_x + n_x + n_x / 2 + n_x / 2 + n_x / 2 +
                             (size_t)BT_ * FF_ / 2 + n_wT + 256;
  const size_t need_bytes  = need_floats * sizeof(float);

  float* ws;
  if (ws_size >= need_bytes) {
    ws = (float*)d_ws;
  } else {
    if (!g_ws_fallback) (void)hipMalloc(&g_ws_fallback, need_bytes);
    ws = (float*)g_ws_fallback;
  }

  size_t off = 0;
  float* x  = ws + off; off += n_x;
  float* qf32 = ws + off; off += n_x;          // bf16 Q buffer; reused as f32 final-LN
  unsigned short* qb = (unsigned short*)qf32;
  unsigned short* kb  = (unsigned short*)(ws + off); off += n_x / 2;
  unsigned short* vtb = (unsigned short*)(ws + off); off += n_x / 2;
  unsigned short* hb  = (unsigned short*)(ws + off); off += n_x / 2;
  unsigned short* ffb = (unsigned short*)(ws + off); off += (size_t)BT_ * FF_ / 2;
  unsigned short* wqT = (unsigned short*)(ws + off);
  unsigned short* wkT = wqT + (size_t)L_ * D_ * D_;
  unsigned short* wvT = wkT + (size_t)L_ * D_ * D_;
  unsigned short* wpT = wvT + (size_t)L_ * D_ * D_;
  unsigned short* w1T = wpT + (size_t)L_ * D_ * D_;
  unsigned short* w2T = w1T + (size_t)L_ * D_ * FF_;
  off += n_wT;
  float* lacc = ws + off;

  zero_kernel<<<1, 1, 0, stream>>>(lacc);
  embed_kernel<<<BT_, 128, 0, stream>>>(idx, tok, pos, x);

  transpose_cvt<<<dim3(2, 16, 48), 256, 0, stream>>>(Wq, wqT, 512, 64, 32768, 32768);
  transpose_cvt<<<dim3(2, 16, 48), 256, 0, stream>>>(Wk, wkT, 512, 64, 32768, 32768);
  transpose_cvt<<<dim3(2, 16, 48), 256, 0, stream>>>(Wv, wvT, 512, 64, 32768, 32768);
  transpose_cvt<<<dim3(16, 16, 6), 256, 0, stream>>>(Wp, wpT, 512, 512, 262144, 262144);
  transpose_cvt<<<dim3(64, 16, 6), 256, 0, stream>>>(W1, w1T, 512, 2048, 1048576, 1048576);
  transpose_cvt<<<dim3(16, 64, 6), 256, 0, stream>>>(W2, w2T, 2048, 512, 1048576, 1048576);

  const dim3 gD(BT_ / 128, D_ / 128);
  const dim3 gF(BT_ / 128, FF_ / 128);

  for (int l = 0; l < L_; ++l) {
    ln_kernel<true><<<BT_ / 4, 256, 0, stream>>>(x, l1s + (size_t)l * D_, l1b + (size_t)l * D_, hb);
    mfma_gemm<false, false, false, 1><<<gD, 256, 0, stream>>>(
        hb, wqT + (size_t)l * D_ * D_, nullptr, qb, D_, D_);
    mfma_gemm<false, false, false, 1><<<gD, 256, 0, stream>>>(
        hb, wkT + (size_t)l * D_ * D_, nullptr, kb, D_, D_);
    mfma_gemm<false, false, false, 2><<<gD, 256, 0, stream>>>(
        hb, wvT + (size_t)l * D_ * D_, nullptr, vtb, D_, D_);
    attn_mfma<<<dim3(T_ / 64, B_ * H_), 256, 0, stream>>>(qb, kb, vtb, hb);
    mfma_gemm<true, false, true, 0><<<gD, 256, 0, stream>>>(
        hb, wpT + (size_t)l * D_ * D_, bp + (size_t)l * D_, x, D_, D_);
    ln_kernel<true><<<BT_ / 4, 256, 0, stream>>>(x, l2s + (size_t)l * D_, l2b + (size_t)l * D_, hb);
    mfma_gemm<false, true, true, 1><<<gF, 256, 0, stream>>>(
        hb, w1T + (size_t)l * D_ * FF_, b1 + (size_t)l * FF_, ffb, D_, FF_);
    mfma_gemm<true, false, true, 0><<<gD, 256, 0, stream>>>(
        ffb, w2T + (size_t)l * FF_ * D_, b2 + (size_t)l * D_, x, FF_, D_);
  }

  ln_kernel<false><<<BT_ / 4, 256, 0, stream>>>(x, lfs, lfb, qf32);
  gemm_f32_kernel<<<dim3(BT_ / 64, 2), 256, 0, stream>>>(
      qf32, D_, Wout, V_, bout, out, V_, D_, V_);
  loss_kernel<<<64, 256, 0, stream>>>(out, targets, lacc);
  loss_finalize_kernel<<<1, 1, 0, stream>>>(lacc, out);
}

// Round 12
// 2188.490 us; speedup vs baseline: 6.3909x; 1.0136x over previous
//
#include <hip/hip_runtime.h>

#define B_  16
#define T_  1024
#define D_  512
#define H_  8
#define L_  6
#define V_  96
#define HS_ 64
#define FF_ 2048
#define BT_ (B_*T_)

typedef __attribute__((ext_vector_type(8))) short bf16x8;
typedef __attribute__((ext_vector_type(4))) float f32x4;

typedef __attribute__((address_space(3))) unsigned int lds_u32_t;
typedef const __attribute__((address_space(1))) unsigned int glb_u32_t;

__device__ __forceinline__ void gload16(const unsigned short* g, unsigned short* l) {
  __builtin_amdgcn_global_load_lds((glb_u32_t*)g, (lds_u32_t*)l, 16, 0, 0);
}

__device__ __forceinline__ unsigned short f2b(float f) {
  unsigned u = __float_as_uint(f);
  unsigned r = (u + 0x7FFFu + ((u >> 16) & 1u)) >> 16;
  return (unsigned short)r;
}

__global__ void zero_kernel(float* p) { p[0] = 0.f; }

// ---------------- embedding ----------------
__global__ __launch_bounds__(128) void embed_kernel(const int* __restrict__ idx,
    const float* __restrict__ tok, const float* __restrict__ pos, float* __restrict__ x) {
  int bt = blockIdx.x;
  int t  = bt & (T_ - 1);
  int id = idx[bt];
  if (id < 0) id = 0; if (id > V_ - 1) id = V_ - 1;
  int d  = threadIdx.x * 4;
  float4 tv = *(const float4*)(tok + (size_t)id * D_ + d);
  float4 pv = *(const float4*)(pos + (size_t)t  * D_ + d);
  float4 o = {tv.x + pv.x, tv.y + pv.y, tv.z + pv.z, tv.w + pv.w};
  *(float4*)(x + (size_t)bt * D_ + d) = o;
}

// ---------------- tiled transpose + f32->bf16: dst[C][R] = src[R][C] ----------------
__global__ __launch_bounds__(256) void transpose_cvt(const float* __restrict__ src,
    unsigned short* __restrict__ dst, int R, int C, long sstride, long dstride) {
  __shared__ float t[32][33];
  const float* s = src + (size_t)blockIdx.z * sstride;
  unsigned short* d = dst + (size_t)blockIdx.z * dstride;
  int r0 = blockIdx.y * 32, c0 = blockIdx.x * 32;
  int tr = threadIdx.x >> 5, tc = threadIdx.x & 31;
#pragma unroll
  for (int i = 0; i < 4; ++i)
    t[tr + i * 8][tc] = s[(size_t)(r0 + tr + i * 8) * C + c0 + tc];
  __syncthreads();
#pragma unroll
  for (int i = 0; i < 4; ++i)
    d[(size_t)(c0 + tr + i * 8) * R + r0 + tc] = f2b(t[tc][tr + i * 8]);
}

// ---------------- layernorm: one wave per row; bf16 or f32 out ----------------
template<bool BF16OUT>
__global__ __launch_bounds__(256) void ln_kernel(const float* __restrict__ x,
    const float* __restrict__ s, const float* __restrict__ b, void* __restrict__ outv) {
  int wave = threadIdx.x >> 6;
  int lane = threadIdx.x & 63;
  int r = blockIdx.x * 4 + wave;
  const float* xr = x + (size_t)r * D_;
  float vals[8];
  float sum = 0.f;
#pragma unroll
  for (int j = 0; j < 8; ++j) { vals[j] = xr[j * 64 + lane]; sum += vals[j]; }
#pragma unroll
  for (int o = 32; o > 0; o >>= 1) sum += __shfl_xor(sum, o, 64);
  float mean = sum * (1.f / D_);
  float vs = 0.f;
#pragma unroll
  for (int j = 0; j < 8; ++j) { float d = vals[j] - mean; vs += d * d; }
#pragma unroll
  for (int o = 32; o > 0; o >>= 1) vs += __shfl_xor(vs, o, 64);
  float rstd = rsqrtf(vs * (1.f / D_) + 1e-5f);
#pragma unroll
  for (int j = 0; j < 8; ++j) {
    int c = j * 64 + lane;
    float v = (vals[j] - mean) * rstd * s[c] + b[c];
    if (BF16OUT) ((unsigned short*)outv)[(size_t)r * D_ + c] = f2b(v);
    else         ((float*)outv)[(size_t)r * D_ + c] = v;
  }
}

// ---------------- bf16 MFMA GEMM: C[M,N] (+)= A[M,K] @ Bt[N,K]^T ----------------
// m97-style: async global_load_lds width=16 staging, unpadded 128x32 bf16 LDS tiles
// (64 B rows; LDS dest = wave-uniform base + lane*16 per the m104/m108 contract).
// OUTMODE: 0 = f32 [M][ldc], 1 = bf16 [M][ldc], 2 = bf16 Vt[(b*H+h)*HS+hs][T]
#define BK 32
template<bool ACC, bool RELU, bool BIAS, int OUTMODE>
__global__ __launch_bounds__(256) void mfma_gemm(
    const unsigned short* __restrict__ A,
    const unsigned short* __restrict__ Bt,
    const float* __restrict__ bias,
    void* __restrict__ Cv,
    int K, int ldc) {
  __shared__ unsigned short Al[128 * BK];
  __shared__ unsigned short Bl[128 * BK];
  const int m0 = blockIdx.x * 128, n0 = blockIdx.y * 128;
  const int tid = threadIdx.x;
  const int lane = tid & 63, wave = tid >> 6;
  const int wy = wave >> 1, wx = wave & 1;
  const int l15 = lane & 15, quad = lane >> 4;

  // staging geometry: wave w covers bytes [w*1024, w*1024+1024) (chunk0, rows w*16..)
  // and +4096 (chunk1, rows 64+w*16..). Lane's global source follows linear order.
  const int sbase = wave * 1024;                 // wave-uniform LDS byte base
  const int soff  = sbase + lane * 16;           // this lane's byte slot
  const int r0 = soff >> 6, c0e = (soff & 63) >> 1;
  const int r1 = r0 + 64;
  const unsigned short* gA0 = A  + (size_t)(m0 + r0) * K + c0e;
  const unsigned short* gA1 = A  + (size_t)(m0 + r1) * K + c0e;
  const unsigned short* gB0 = Bt + (size_t)(n0 + r0) * K + c0e;
  const unsigned short* gB1 = Bt + (size_t)(n0 + r1) * K + c0e;
  unsigned short* lA0 = &Al[sbase >> 1];
  unsigned short* lA1 = &Al[(sbase + 4096) >> 1];
  unsigned short* lB0 = &Bl[sbase >> 1];
  unsigned short* lB1 = &Bl[(sbase + 4096) >> 1];

  f32x4 acc[4][4];
  const f32x4 z4 = {0.f, 0.f, 0.f, 0.f};
#pragma unroll
  for (int mi = 0; mi < 4; ++mi)
#pragma unroll
    for (int ni = 0; ni < 4; ++ni) acc[mi][ni] = z4;

  for (int k0 = 0; k0 < K; k0 += BK) {
    gload16(gA0 + k0, lA0);
    gload16(gA1 + k0, lA1);
    gload16(gB0 + k0, lB0);
    gload16(gB1 + k0, lB1);
    __syncthreads();
    bf16x8 af[4], bfr[4];
#pragma unroll
    for (int mi = 0; mi < 4; ++mi)
      af[mi] = *(const bf16x8*)(&Al[(wy * 64 + mi * 16 + l15) * BK + quad * 8]);
#pragma unroll
    for (int ni = 0; ni < 4; ++ni)
      bfr[ni] = *(const bf16x8*)(&Bl[(wx * 64 + ni * 16 + l15) * BK + quad * 8]);
#pragma unroll
    for (int mi = 0; mi < 4; ++mi)
#pragma unroll
      for (int ni = 0; ni < 4; ++ni)
        acc[mi][ni] = __builtin_amdgcn_mfma_f32_16x16x32_bf16(af[mi], bfr[ni], acc[mi][ni], 0, 0, 0);
    __syncthreads();
  }
#pragma unroll
  for (int mi = 0; mi < 4; ++mi) {
    int row0 = m0 + wy * 64 + mi * 16 + quad * 4;
#pragma unroll
    for (int ni = 0; ni < 4; ++ni) {
      int col = n0 + wx * 64 + ni * 16 + l15;
      float bb = BIAS ? bias[col] : 0.f;
#pragma unroll
      for (int r = 0; r < 4; ++r) {
        float v = acc[mi][ni][r] + bb;
        if (RELU) v = fmaxf(v, 0.f);
        int row = row0 + r;
        if (OUTMODE == 2) {
          int b = row >> 10, t = row & (T_ - 1);
          int h = col >> 6, hs = col & 63;
          ((unsigned short*)Cv)[((size_t)((b * H_ + h) * HS_ + hs)) * T_ + t] = f2b(v);
        } else {
          size_t off = (size_t)row * ldc + col;
          if (ACC) v += ((const float*)Cv)[off];
          if (OUTMODE == 1) ((unsigned short*)Cv)[off] = f2b(v);
          else              ((float*)Cv)[off] = v;
        }
      }
    }
  }
}

// ---------------- MFMA flash attention, no-max softmax ----------------
#define PSTR 72
__global__ __launch_bounds__(256) void attn_mfma(const unsigned short* __restrict__ q,
    const unsigned short* __restrict__ k, const unsigned short* __restrict__ vt,
    unsigned short* __restrict__ o) {
  __shared__ unsigned short Pbuf[2][64 * PSTR];
  const int qt = (gridDim.x - 1) - blockIdx.x;   // heavy tiles dispatch first
  const int bh = blockIdx.y;
  const int b = bh >> 3, hh = bh & 7;
  const int tid = threadIdx.x;
  const int lane = tid & 63, w = tid >> 6;
  const int l15 = lane & 15, quad = lane >> 4;
  const float CEXP = 0.044194173824159216f * 1.4426950408889634f;  // scale*log2(e)

  bf16x8 qf[4][2];
#pragma unroll
  for (int mi = 0; mi < 4; ++mi)
#pragma unroll
    for (int c = 0; c < 2; ++c)
      qf[mi][c] = *(const bf16x8*)(q + (size_t)(b * T_ + qt * 64 + mi * 16 + l15) * D_
                                     + hh * HS_ + c * 32 + quad * 8);

  const short one_bf = (short)0x3F80;
  bf16x8 ones = {one_bf, one_bf, one_bf, one_bf, one_bf, one_bf, one_bf, one_bf};

  f32x4 oacc[4], lacc[4];
  const f32x4 z4 = {0.f, 0.f, 0.f, 0.f};
#pragma unroll
  for (int mi = 0; mi < 4; ++mi) { oacc[mi] = z4; lacc[mi] = z4; }

  for (int kt = 0; kt <= qt; ++kt) {
    f32x4 s[4];
#pragma unroll
    for (int mi = 0; mi < 4; ++mi) s[mi] = z4;
#pragma unroll
    for (int c = 0; c < 2; ++c) {
      bf16x8 kf = *(const bf16x8*)(k + (size_t)(b * T_ + kt * 64 + w * 16 + l15) * D_
                                     + hh * HS_ + c * 32 + quad * 8);
#pragma unroll
      for (int mi = 0; mi < 4; ++mi)
        s[mi] = __builtin_amdgcn_mfma_f32_16x16x32_bf16(qf[mi][c], kf, s[mi], 0, 0, 0);
    }
    unsigned short* pb = Pbuf[kt & 1];
    if (kt == qt) {
#pragma unroll
      for (int mi = 0; mi < 4; ++mi)
#pragma unroll
        for (int r = 0; r < 4; ++r) {
          int row = mi * 16 + quad * 4 + r;
          int gc = w * 16 + l15;
          float p = (gc > row) ? 0.f : exp2f(s[mi][r] * CEXP);
          pb[row * PSTR + gc] = f2b(p);
        }
    } else {
#pragma unroll
      for (int mi = 0; mi < 4; ++mi)
#pragma unroll
        for (int r = 0; r < 4; ++r) {
          int row = mi * 16 + quad * 4 + r;
          pb[row * PSTR + w * 16 + l15] = f2b(exp2f(s[mi][r] * CEXP));
        }
    }
    __syncthreads();
#pragma unroll
    for (int c = 0; c < 2; ++c) {
      bf16x8 vf = *(const bf16x8*)(vt + ((size_t)(bh * HS_ + w * 16 + l15)) * T_
                                      + kt * 64 + c * 32 + quad * 8);
#pragma unroll
      for (int mi = 0; mi < 4; ++mi) {
        bf16x8 pf = *(const bf16x8*)(&pb[(mi * 16 + l15) * PSTR + c * 32 + quad * 8]);
        oacc[mi] = __builtin_amdgcn_mfma_f32_16x16x32_bf16(pf, vf, oacc[mi], 0, 0, 0);
        lacc[mi] = __builtin_amdgcn_mfma_f32_16x16x32_bf16(pf, ones, lacc[mi], 0, 0, 0);
      }
    }
  }
#pragma unroll
  for (int mi = 0; mi < 4; ++mi)
#pragma unroll
    for (int r = 0; r < 4; ++r) {
      int row = mi * 16 + quad * 4 + r;
      float inv = 1.f / lacc[mi][r];
      o[(size_t)(b * T_ + qt * 64 + row) * D_ + hh * HS_ + w * 16 + l15] =
          f2b(oacc[mi][r] * inv);
    }
}

// ---------------- f32 tiled GEMM (logits only) ----------------
__global__ __launch_bounds__(256) void gemm_f32_kernel(const float* __restrict__ A, int lda,
    const float* __restrict__ Bw, int ldb, const float* __restrict__ bias,
    float* __restrict__ C, int ldc, int K, int N) {
  __shared__ float As[16][64];
  __shared__ float Bs[16][64];
  int n0 = blockIdx.y * 64;
  int nv = N - n0; if (nv > 64) nv = 64;
  int m0 = blockIdx.x * 64;
  const int tid = threadIdx.x;
  const int tx = tid & 15, ty = tid >> 4;
  const int amm = tid >> 2;
  const int akk = (tid & 3) * 4;
  const int bkk = tid >> 4;
  const int bnn = (tid & 15) * 4;
  float acc[4][4] = {};
  for (int k0 = 0; k0 < K; k0 += 16) {
    float4 av = *(const float4*)(A + (size_t)(m0 + amm) * lda + k0 + akk);
    As[akk + 0][amm] = av.x; As[akk + 1][amm] = av.y;
    As[akk + 2][amm] = av.z; As[akk + 3][amm] = av.w;
    if (bnn < nv) {
      float4 bv = *(const float4*)(Bw + (size_t)(k0 + bkk) * ldb + n0 + bnn);
      Bs[bkk][bnn + 0] = bv.x; Bs[bkk][bnn + 1] = bv.y;
      Bs[bkk][bnn + 2] = bv.z; Bs[bkk][bnn + 3] = bv.w;
    } else {
      Bs[bkk][bnn + 0] = 0.f; Bs[bkk][bnn + 1] = 0.f;
      Bs[bkk][bnn + 2] = 0.f; Bs[bkk][bnn + 3] = 0.f;
    }
    __syncthreads();
#pragma unroll
    for (int kk = 0; kk < 16; ++kk) {
      float4 a4 = *(const float4*)(&As[kk][ty * 4]);
      float4 b4 = *(const float4*)(&Bs[kk][tx * 4]);
      float aa[4] = {a4.x, a4.y, a4.z, a4.w};
      float bb[4] = {b4.x, b4.y, b4.z, b4.w};
#pragma unroll
      for (int i = 0; i < 4; ++i)
#pragma unroll
        for (int j = 0; j < 4; ++j)
          acc[i][j] = fmaf(aa[i], bb[j], acc[i][j]);
    }
    __syncthreads();
  }
  if (tx * 4 < nv) {
#pragma unroll
    for (int i = 0; i < 4; ++i) {
      float* cp = C + (size_t)(m0 + ty * 4 + i) * ldc + n0 + tx * 4;
      float4 st = {acc[i][0] + bias[n0 + tx * 4 + 0], acc[i][1] + bias[n0 + tx * 4 + 1],
                   acc[i][2] + bias[n0 + tx * 4 + 2], acc[i][3] + bias[n0 + tx * 4 + 3]};
      *(float4*)cp = st;
    }
  }
}

// ---------------- loss: hierarchical reduction, one atomic per block ----------------
__global__ __launch_bounds__(256) void loss_kernel(const float* __restrict__ logits,
    const int* __restrict__ targets, float* __restrict__ loss_acc) {
  __shared__ float wsum[4];
  int wave = threadIdx.x >> 6, lane = threadIdx.x & 63;
  float local = 0.f;
  for (int r = blockIdx.x * 4 + wave; r < BT_; r += gridDim.x * 4) {
    const float* lr = logits + (size_t)r * V_;
    float v0 = lr[lane];
    float v1 = (lane < 32) ? lr[64 + lane] : -INFINITY;
    float mx = fmaxf(v0, v1);
#pragma unroll
    for (int o = 32; o > 0; o >>= 1) mx = fmaxf(mx, __shfl_xor(mx, o, 64));
    float se = expf(v0 - mx) + ((lane < 32) ? expf(v1 - mx) : 0.f);
#pragma unroll
    for (int o = 32; o > 0; o >>= 1) se += __shfl_xor(se, o, 64);
    if (lane == 0) {
      int tg = targets[r];
      if (tg < 0) tg = 0; if (tg > V_ - 1) tg = V_ - 1;
      local += (mx + logf(se)) - lr[tg];
    }
  }
  if (lane == 0) wsum[wave] = local;
  __syncthreads();
  if (threadIdx.x == 0)
    atomicAdd(loss_acc, wsum[0] + wsum[1] + wsum[2] + wsum[3]);
}

__global__ void loss_finalize_kernel(const float* __restrict__ acc, float* __restrict__ out) {
  out[(size_t)BT_ * V_] = acc[0] * (1.f / BT_);
}

// ---------------- host ----------------
static void* g_ws_fallback = nullptr;

extern "C" void kernel_launch(void* const* d_in, const int* in_sizes, int n_in,
                              void* d_out, int out_size, void* d_ws, size_t ws_size,
                              hipStream_t stream) {
  const int*   idx     = (const int*)d_in[0];
  const int*   targets = (const int*)d_in[1];
  const float* tok  = (const float*)d_in[2];
  const float* pos  = (const float*)d_in[3];
  const float* Wq   = (const float*)d_in[4];
  const float* Wk   = (const float*)d_in[5];
  const float* Wv   = (const float*)d_in[6];
  const float* Wp   = (const float*)d_in[7];
  const float* bp   = (const float*)d_in[8];
  const float* W1   = (const float*)d_in[9];
  const float* b1   = (const float*)d_in[10];
  const float* W2   = (const float*)d_in[11];
  const float* b2   = (const float*)d_in[12];
  const float* l1s  = (const float*)d_in[13];
  const float* l1b  = (const float*)d_in[14];
  const float* l2s  = (const float*)d_in[15];
  const float* l2b  = (const float*)d_in[16];
  const float* lfs  = (const float*)d_in[17];
  const float* lfb  = (const float*)d_in[18];
  const float* Wout = (const float*)d_in[19];
  const float* bout = (const float*)d_in[20];
  float* out = (float*)d_out;   // f32 logits + f32 loss scalar

  const size_t n_x  = (size_t)BT_ * D_;
  const size_t n_wT = 9437184;   // transposed bf16 weights (f32-equiv)
  const size_t need_floats = n_x + n_x + n_x / 2 + n_x / 2 + n_x / 2 +
                             (size_t)BT_ * FF_ / 2 + n_wT + 256;
  const size_t need_bytes  = need_floats * sizeof(float);

  float* ws;
  if (ws_size >= need_bytes) {
    ws = (float*)d_ws;
  } else {
    if (!g_ws_fallback) (void)hipMalloc(&g_ws_fallback, need_bytes);
    ws = (float*)g_ws_fallback;
  }

  size_t off = 0;
  float* x  = ws + off; off += n_x;
  float* qf32 = ws + off; off += n_x;          // bf16 Q buffer; reused as f32 final-LN
  unsigned short* qb = (unsigned short*)qf32;
  unsigned short* kb  = (unsigned short*)(ws + off); off += n_x / 2;
  unsigned short* vtb = (unsigned short*)(ws + off); off += n_x / 2;
  unsigned short* hb  = (unsigned short*)(ws + off); off += n_x / 2;
  unsigned short* ffb = (unsigned short*)(ws + off); off += (size_t)BT_ * FF_ / 2;
  unsigned short* wqT = (unsigned short*)(ws + off);
  unsigned short* wkT = wqT + (size_t)L_ * D_ * D_;
  unsigned short* wvT = wkT + (size_t)L_ * D_ * D_;
  unsigned short* wpT = wvT + (size_t)L_ * D_ * D_;
  unsigned short* w1T = wpT + (size_t)L_ * D_ * D_;
  unsigned short* w2T = w1T + (size_t)L_ * D_ * FF_;
  off += n_wT;
  float* lacc = ws + off;

  zero_kernel<<<1, 1, 0, stream>>>(lacc);
  embed_kernel<<<BT_, 128, 0, stream>>>(idx, tok, pos, x);

  transpose_cvt<<<dim3(2, 16, 48), 256, 0, stream>>>(Wq, wqT, 512, 64, 32768, 32768);
  transpose_cvt<<<dim3(2, 16, 48), 256, 0, stream>>>(Wk, wkT, 512, 64, 32768, 32768);
  transpose_cvt<<<dim3(2, 16, 48), 256, 0, stream>>>(Wv, wvT, 512, 64, 32768, 32768);
  transpose_cvt<<<dim3(16, 16, 6), 256, 0, stream>>>(Wp, wpT, 512, 512, 262144, 262144);
  transpose_cvt<<<dim3(64, 16, 6), 256, 0, stream>>>(W1, w1T, 512, 2048, 1048576, 1048576);
  transpose_cvt<<<dim3(16, 64, 6), 256, 0, stream>>>(W2, w2T, 2048, 512, 1048576, 1048576);

  const dim3 gD(BT_ / 128, D_ / 128);
  const dim3 gF(BT_ / 128, FF_ / 128);

  for (int l = 0; l < L_; ++l) {
    ln_kernel<true><<<BT_ / 4, 256, 0, stream>>>(x, l1s + (size_t)l * D_, l1b + (size_t)l * D_, hb);
    mfma_gemm<false, false, false, 1><<<gD, 256, 0, stream>>>(
        hb, wqT + (size_t)l * D_ * D_, nullptr, qb, D_, D_);
    mfma_gemm<false, false, false, 1><<<gD, 256, 0, stream>>>(
        hb, wkT + (size_t)l * D_ * D_, nullptr, kb, D_, D_);
    mfma_gemm<false, false, false, 2><<<gD, 256, 0, stream>>>(
        hb, wvT + (size_t)l * D_ * D_, nullptr, vtb, D_, D_);
    attn_mfma<<<dim3(T_ / 64, B_ * H_), 256, 0, stream>>>(qb, kb, vtb, hb);
    mfma_gemm<true, false, true, 0><<<gD, 256, 0, stream>>>(
        hb, wpT + (size_t)l * D_ * D_, bp + (size_t)l * D_, x, D_, D_);
    ln_kernel<true><<<BT_ / 4, 256, 0, stream>>>(x, l2s + (size_t)l * D_, l2b + (size_t)l * D_, hb);
    mfma_gemm<false, true, true, 1><<<gF, 256, 0, stream>>>(
        hb, w1T + (size_t)l * D_ * FF_, b1 + (size_t)l * FF_, ffb, D_, FF_);
    mfma_gemm<true, false, true, 0><<<gD, 256, 0, stream>>>(
        ffb, w2T + (size_t)l * FF_ * D_, b2 + (size_t)l * D_, x, FF_, D_);
  }

  ln_kernel<false><<<BT_ / 4, 256, 0, stream>>>(x, lfs, lfb, qf32);
  gemm_f32_kernel<<<dim3(BT_ / 64, 2), 256, 0, stream>>>(
      qf32, D_, Wout, V_, bout, out, V_, D_, V_);
  loss_kernel<<<64, 256, 0, stream>>>(out, targets, lacc);
  loss_finalize_kernel<<<1, 1, 0, stream>>>(lacc, out);
}